// Round 5
// baseline (224.811 us; speedup 1.0000x reference)
//
#include <hip/hip_runtime.h>
#include <math.h>

#define B_ 2
#define L_ 1024
#define D_ 512
#define NROW 2048
#define RS 288                  // R stride: key16|query16|g1 256
#define PI_F 3.14159274f
#define TWO_PI_F 6.28318548f

typedef __attribute__((ext_vector_type(8))) short bf16x8;
typedef __attribute__((ext_vector_type(4))) float f32x4;

__device__ __forceinline__ unsigned short f2bf(float f) {
    unsigned u = __float_as_uint(f);
    unsigned r = (u + 0x7FFFu + ((u >> 16) & 1u)) >> 16;
    return (unsigned short)r;
}
__device__ __forceinline__ float bf2f(unsigned short h) {
    return __uint_as_float((unsigned)h << 16);
}
__device__ __forceinline__ unsigned pack2(float a, float b) {
    return (unsigned)f2bf(a) | ((unsigned)f2bf(b) << 16);
}

// ---------------- weight prep: tiled transpose + bf16 cast (verified R1) + rowsum zero ----------------
// W[1408][512] bf16, n-major: rows 0-15 key, 16-31 query, 32-287 g1, 288-799 v, 800-895 zero, 896-1407 out_w^T
__global__ __launch_bounds__(256) void k_prep_w(
    const float* __restrict__ keyw, const float* __restrict__ qryw,
    const float* __restrict__ g1w, const float* __restrict__ vw,
    const float* __restrict__ outw, unsigned short* __restrict__ W,
    float* __restrict__ rowsum)
{
    if (blockIdx.x < 16) rowsum[(blockIdx.x << 8) + threadIdx.x] = 0.f;
    const int nt = blockIdx.x % 22;
    const int kt = blockIdx.x / 22;     // 0..7
    const int n0 = nt * 64, k0 = kt * 64;
    __shared__ unsigned short tile[64 * 68];   // [k][n], stride 68
    const int tn = threadIdx.x & 63;
    const int tk4 = threadIdx.x >> 6;   // 0..3
    const int n = n0 + tn;
    const float* src = nullptr; int stride = 0, col = 0;
    if (n < 16)        { src = keyw; stride = 16;  col = n; }
    else if (n < 32)   { src = qryw; stride = 16;  col = n - 16; }
    else if (n < 288)  { src = g1w;  stride = 256; col = n - 32; }
    else if (n < 800)  { src = vw;   stride = 512; col = n - 288; }
    else if (n < 896)  { src = nullptr; }
    else               { src = outw; stride = 512; col = n - 896; }
    #pragma unroll
    for (int r = 0; r < 16; ++r) {
        int k = k0 + tk4 * 16 + r;
        float v = src ? src[(size_t)k * stride + col] : 0.f;
        tile[(tk4 * 16 + r) * 68 + tn] = f2bf(v);
    }
    __syncthreads();
    #pragma unroll
    for (int r = 0; r < 16; ++r) {
        int nn = n0 + tk4 * 16 + r;
        W[(size_t)nn * 512 + k0 + tn] = tile[tn * 68 + tk4 * 16 + r];
    }
}

// ---------------- GEMM1: R[2048][288] (k/q/g1) + Vt hi/lo (V region) ----------------
// B from prepped bf16 W (int4 staging, verified R3); V epilogue direct-transposed (verified R4)
__global__ __launch_bounds__(256) void k_gemm1v(
    const float* __restrict__ x,
    const unsigned short* __restrict__ Bt,   // W[0:896][512] bf16 n-major
    const float* __restrict__ g1b, const float* __restrict__ vb,
    float* __restrict__ R,
    unsigned short* __restrict__ Vthi, unsigned short* __restrict__ Vtlo)
{
    __shared__ unsigned short As[64 * 32];
    __shared__ unsigned short Bs[128 * 32];
    const int tid = threadIdx.x;
    const int w = tid >> 6;
    const int lane = tid & 63;
    const int m0 = blockIdx.y * 64;
    const int n0 = blockIdx.x * 128;
    const int srow = tid >> 2;          // 0..63
    const int scol = (tid & 3) * 8;     // 0,8,16,24
    const int quad = lane >> 4, r16 = lane & 15;

    f32x4 acc[4][2];
    #pragma unroll
    for (int mt = 0; mt < 4; ++mt)
        #pragma unroll
        for (int nt = 0; nt < 2; ++nt)
            acc[mt][nt] = (f32x4){0.f, 0.f, 0.f, 0.f};

    const float* ap = x + (size_t)(m0 + srow) * 512 + scol;
    const unsigned short* bp0 = Bt + (size_t)(n0 + srow) * 512 + scol;
    const unsigned short* bp1 = Bt + (size_t)(n0 + 64 + srow) * 512 + scol;

    for (int k0 = 0; k0 < 512; k0 += 32) {
        float4 a0 = *(const float4*)(ap + k0);
        float4 a1 = *(const float4*)(ap + k0 + 4);
        int4 bv0 = *(const int4*)(bp0 + k0);
        int4 bv1 = *(const int4*)(bp1 + k0);
        int4 av;
        av.x = (int)f2bf(a0.x) | ((int)f2bf(a0.y) << 16);
        av.y = (int)f2bf(a0.z) | ((int)f2bf(a0.w) << 16);
        av.z = (int)f2bf(a1.x) | ((int)f2bf(a1.y) << 16);
        av.w = (int)f2bf(a1.z) | ((int)f2bf(a1.w) << 16);
        __syncthreads();
        *(int4*)&As[srow * 32 + scol] = av;
        *(int4*)&Bs[srow * 32 + scol] = bv0;
        *(int4*)&Bs[(64 + srow) * 32 + scol] = bv1;
        __syncthreads();
        bf16x8 af[4], bfr[2];
        #pragma unroll
        for (int mt = 0; mt < 4; ++mt)
            af[mt] = *(const bf16x8*)&As[(mt * 16 + r16) * 32 + quad * 8];
        #pragma unroll
        for (int nt = 0; nt < 2; ++nt)
            bfr[nt] = *(const bf16x8*)&Bs[(w * 32 + nt * 16 + r16) * 32 + quad * 8];
        #pragma unroll
        for (int mt = 0; mt < 4; ++mt)
            #pragma unroll
            for (int nt = 0; nt < 2; ++nt)
                acc[mt][nt] = __builtin_amdgcn_mfma_f32_16x16x32_bf16(
                    af[mt], bfr[nt], acc[mt][nt], 0, 0, 0);
    }

    #pragma unroll
    for (int mt = 0; mt < 4; ++mt) {
        #pragma unroll
        for (int nt = 0; nt < 2; ++nt) {
            const int n = n0 + w * 32 + nt * 16 + r16;
            if (n < 288) {
                float bias = (n >= 32) ? g1b[n - 32] : 0.f;
                #pragma unroll
                for (int i = 0; i < 4; ++i) {
                    const int m = m0 + mt * 16 + quad * 4 + i;
                    R[(size_t)m * RS + n] = acc[mt][nt][i] + bias;
                }
            } else if (n < 800) {
                const int d = n - 288;
                const float bias = vb[d];
                ushort4 h4, l4;
                #pragma unroll
                for (int i = 0; i < 4; ++i) {
                    float v = acc[mt][nt][i] + bias;
                    unsigned short hi = f2bf(v);
                    ((unsigned short*)&h4)[i] = hi;
                    ((unsigned short*)&l4)[i] = f2bf(v - bf2f(hi));
                }
                const size_t vo = (size_t)d * 2048 + m0 + mt * 16 + quad * 4;
                *(ushort4*)&Vthi[vo] = h4;
                *(ushort4*)&Vtlo[vo] = l4;
            }
        }
    }
}

// ---------------- phasors, jk/jq, gate (verified) ----------------
__global__ __launch_bounds__(256) void k_phasor(
    const float* __restrict__ R,
    const float* __restrict__ g2w, const float* __restrict__ g2b,
    float* __restrict__ scal)
{
    const int row = blockIdx.x * 4 + (threadIdx.x >> 6);
    const int lane = threadIdx.x & 63;
    float* sc = scal + (size_t)row * 128;
    const float* r = R + (size_t)row * RS;

    float part = 0.f;
    #pragma unroll
    for (int j = 0; j < 4; ++j) {
        float v = r[32 + lane * 4 + j];
        float h = 0.5f * v * (1.0f + erff(v * 0.70710678f));
        part += h * g2w[lane * 4 + j];
    }
    #pragma unroll
    for (int off = 32; off > 0; off >>= 1) part += __shfl_down(part, off, 64);
    if (lane == 0) sc[112] = 1.0f / (1.0f + expf(-(part + g2b[0])));

    float pr = 1.f, pim = 0.f;
    if (lane < 32) {
        float a = tanhf(r[lane]) * PI_F;
        float sv, cv;
        sincosf(a, &sv, &cv);
        int t = lane & 15;
        if (lane < 16) { sc[t] = cv; sc[16 + t] = sv; }
        else           { sc[32 + t] = cv; sc[48 + t] = sv; }
        pr = cv; pim = sv;
    }
    #pragma unroll
    for (int m = 4; m <= 8; m <<= 1) {
        float orr = __shfl_xor(pr, m, 64);
        float oii = __shfl_xor(pim, m, 64);
        float nr = pr * orr - pim * oii;
        float ni = pr * oii + pim * orr;
        pr = nr; pim = ni;
    }
    if (lane < 4)                     { sc[64 + lane] = pr; sc[68 + lane] = pim; }
    else if (lane >= 16 && lane < 20) { sc[72 + lane - 16] = pr; sc[76 + lane - 16] = pim; }
}

// ---------------- wg scan + surprise gate + Qf/Kf build + gtab (verified R4) ----------------
__global__ __launch_bounds__(1024) void k_wg2(
    const float* __restrict__ scal, const float* __restrict__ pf,
    const float* __restrict__ res_scale, const float* __restrict__ res_thr,
    const float* __restrict__ sur_scale, const float* __restrict__ sur_bias,
    const float* __restrict__ setw,
    float* __restrict__ gtab,
    unsigned short* __restrict__ Qf, unsigned short* __restrict__ Kf)
{
    const int b = blockIdx.x;
    const int l = threadIdx.x;
    if (b == B_) {
        float g = 0.f;
        #pragma unroll
        for (int p = 0; p < 16; ++p)
            g += cosf(TWO_PI_F * (float)l * pf[p]);
        gtab[l] = g;
        return;
    }
    const size_t row = (size_t)(b * L_ + l) * 128;
    float v[8], own[8];
    #pragma unroll
    for (int c2 = 0; c2 < 8; ++c2) { v[c2] = scal[row + 64 + c2]; own[c2] = v[c2]; }
    const int lane = l & 63;
    const int wave = l >> 6;
    #pragma unroll
    for (int off = 1; off < 64; off <<= 1) {
        float o[8];
        #pragma unroll
        for (int c2 = 0; c2 < 8; ++c2) o[c2] = __shfl_up(v[c2], off, 64);
        if (lane >= off) {
            #pragma unroll
            for (int c2 = 0; c2 < 8; ++c2) v[c2] += o[c2];
        }
    }
    __shared__ float wtot[16][8];
    if (lane == 63) {
        #pragma unroll
        for (int c2 = 0; c2 < 8; ++c2) wtot[wave][c2] = v[c2];
    }
    __syncthreads();
    float pre[8] = {0,0,0,0,0,0,0,0};
    for (int w2 = 0; w2 < wave; ++w2) {
        #pragma unroll
        for (int c2 = 0; c2 < 8; ++c2) pre[c2] += wtot[w2][c2];
    }
    float km[8];
    #pragma unroll
    for (int c2 = 0; c2 < 8; ++c2) km[c2] = pre[c2] + v[c2] - own[c2];
    float mag = 0.f;
    #pragma unroll
    for (int pp = 0; pp < 4; ++pp) {
        float jqr = scal[row + 72 + pp], jqi = scal[row + 76 + pp];
        float re = km[pp] * jqr + km[4 + pp] * jqi;
        float im = km[4 + pp] * jqr - km[pp] * jqi;
        mag += sqrtf(re * re + im * im);
    }
    mag *= 0.25f;
    float posn = fmaxf((float)l, 1.0f);
    float nres = mag / sqrtf(posn);
    float scl = fminf(fmaxf(res_scale[0], 1.0f), 20.0f);
    float thr = fminf(fmaxf(res_thr[0], 0.1f), 0.9f);
    float sur = 0.5f * (1.0f - tanhf(scl * (nres - thr)));
    float wgv = 1.0f / (1.0f + expf(-(sur_scale[0] * (sur - 0.5f) + sur_bias[0])));

    const float gate = scal[row + 112];
    float s0 = setw[0], s1 = setw[1], s2 = setw[2], s3 = setw[3];
    float mx = fmaxf(fmaxf(s0, s1), fmaxf(s2, s3));
    float e0 = expf(s0 - mx), e1 = expf(s1 - mx), e2 = expf(s2 - mx), e3 = expf(s3 - mx);
    float esum = e0 + e1 + e2 + e3;
    float w4[4] = {e0 / esum, e1 / esum, e2 / esum, e3 / esum};
    const float qs = 0.2f * gate;

    unsigned* qp = (unsigned*)(Qf + (size_t)(b * L_ + l) * 64);
    unsigned* kp = (unsigned*)(Kf + (size_t)(b * L_ + l) * 64);
    #pragma unroll
    for (int s = 0; s < 16; ++s) {
        float wgrp = w4[s >> 2];
        qp[s] = pack2(qs * wgrp * scal[row + 32 + s], qs * wgrp * scal[row + 48 + s]);
        kp[s] = pack2(wgv * scal[row + s], wgv * scal[row + 16 + s]);
    }
    #pragma unroll
    for (int p = 0; p < 4; ++p) {
        qp[16 + p] = pack2(qs * scal[row + 72 + p], qs * scal[row + 76 + p]);
        kp[16 + p] = pack2(wgv * scal[row + 64 + p], wgv * scal[row + 68 + p]);
    }
    #pragma unroll
    for (int s = 20; s < 32; ++s) { qp[s] = 0u; kp[s] = 0u; }
}

// ---------------- fused A-build + AV GEMM: A-tile through LDS, never global ----------------
// block = (b, ti desc, nj). Loops tj=0..ti: QK MFMA -> toeplitz/mask -> hi/lo LDS -> AV MFMA.
__global__ __launch_bounds__(256) void k_avF(
    const unsigned short* __restrict__ Qf, const unsigned short* __restrict__ Kf,
    const float* __restrict__ scal, const float* __restrict__ gtab,
    const float* __restrict__ posw,
    const unsigned short* __restrict__ Vthi, const unsigned short* __restrict__ Vtlo,
    float* __restrict__ loc, float* __restrict__ rowsum)
{
    const int bx = blockIdx.x;           // 2*16*8 = 256
    const int b  = bx >> 7;
    const int ti = 15 - ((bx >> 3) & 15);   // descending: big blocks first
    const int nj = bx & 7;
    const int m0 = ti * 64, n0 = nj * 64;

    __shared__ unsigned short Qs[64 * 72];
    __shared__ unsigned short Ks[64 * 72];
    __shared__ unsigned short Ah[64 * 68];
    __shared__ unsigned short Al[64 * 68];
    __shared__ unsigned short Bh[64 * 68];
    __shared__ unsigned short Bl[64 * 68];
    __shared__ float gS[64];
    __shared__ float redS[4][64], redQ[4][64];

    const int tid = threadIdx.x;
    const int w = tid >> 6, lane = tid & 63;
    const int quad = lane >> 4, r16 = lane & 15;
    const int srow = tid >> 2;           // 0..63
    const int sc16 = (tid & 3) * 16;     // 0,16,32,48

    {   // stage Q tile once
        const unsigned short* qsrc = Qf + ((size_t)(b * L_ + m0 + srow)) * 64 + sc16;
        *(int4*)&Qs[srow * 72 + sc16]     = *(const int4*)(qsrc);
        *(int4*)&Qs[srow * 72 + sc16 + 8] = *(const int4*)(qsrc + 8);
    }
    if (tid < 64) gS[tid] = scal[((size_t)(b * L_ + m0 + tid)) * 128 + 112];
    const float sw = 1.0f / (1.0f + expf(-posw[0]));

    f32x4 accV[4];
    #pragma unroll
    for (int mt = 0; mt < 4; ++mt) accV[mt] = (f32x4){0.f, 0.f, 0.f, 0.f};

    for (int tj = 0; tj <= ti; ++tj) {
        __syncthreads();   // prior QK/AV reads of Ks/Bh/Bl done (also covers Qs/gS first use)
        {
            const unsigned short* ksrc = Kf + ((size_t)(b * L_ + tj * 64 + srow)) * 64 + sc16;
            *(int4*)&Ks[srow * 72 + sc16]     = *(const int4*)(ksrc);
            *(int4*)&Ks[srow * 72 + sc16 + 8] = *(const int4*)(ksrc + 8);
            const size_t vo = (size_t)(n0 + srow) * 2048 + b * L_ + tj * 64 + sc16;
            *(int4*)&Bh[srow * 68 + sc16]     = *(const int4*)(Vthi + vo);
            *(int4*)&Bh[srow * 68 + sc16 + 8] = *(const int4*)(Vthi + vo + 8);
            *(int4*)&Bl[srow * 68 + sc16]     = *(const int4*)(Vtlo + vo);
            *(int4*)&Bl[srow * 68 + sc16 + 8] = *(const int4*)(Vtlo + vo + 8);
        }
        __syncthreads();   // staged

        // QK^T 64x64 tile
        f32x4 a4[4];
        #pragma unroll
        for (int mt = 0; mt < 4; ++mt) a4[mt] = (f32x4){0.f, 0.f, 0.f, 0.f};
        #pragma unroll
        for (int kk = 0; kk < 2; ++kk) {
            bf16x8 bfr = *(const bf16x8*)&Ks[(w * 16 + r16) * 72 + kk * 32 + quad * 8];
            #pragma unroll
            for (int mt = 0; mt < 4; ++mt) {
                bf16x8 af = *(const bf16x8*)&Qs[(mt * 16 + r16) * 72 + kk * 32 + quad * 8];
                a4[mt] = __builtin_amdgcn_mfma_f32_16x16x32_bf16(af, bfr, a4[mt], 0, 0, 0);
            }
        }
        // toeplitz + causal mask -> hi/lo bf16 into LDS
        const int lp = tj * 64 + w * 16 + r16;
        #pragma unroll
        for (int mt = 0; mt < 4; ++mt) {
            #pragma unroll
            for (int i = 0; i < 4; ++i) {
                const int lr = mt * 16 + quad * 4 + i;      // local row
                const int dl = (m0 + lr) - lp;
                float v = 0.f;
                if (dl >= 0)
                    v = a4[mt][i] + (1.0f - gS[lr]) * sw * gtab[dl];
                unsigned short hi = f2bf(v);
                Ah[lr * 68 + w * 16 + r16] = hi;
                Al[lr * 68 + w * 16 + r16] = f2bf(v - bf2f(hi));
            }
        }
        __syncthreads();   // A ready

        // AV: 64-k in two 32-k halves, hi/lo 3 products
        #pragma unroll
        for (int kh = 0; kh < 2; ++kh) {
            bf16x8 bh8 = *(const bf16x8*)&Bh[(w * 16 + r16) * 68 + kh * 32 + quad * 8];
            bf16x8 bl8 = *(const bf16x8*)&Bl[(w * 16 + r16) * 68 + kh * 32 + quad * 8];
            #pragma unroll
            for (int mt = 0; mt < 4; ++mt) {
                bf16x8 ah8 = *(const bf16x8*)&Ah[(mt * 16 + r16) * 68 + kh * 32 + quad * 8];
                bf16x8 al8 = *(const bf16x8*)&Al[(mt * 16 + r16) * 68 + kh * 32 + quad * 8];
                accV[mt] = __builtin_amdgcn_mfma_f32_16x16x32_bf16(ah8, bh8, accV[mt], 0, 0, 0);
                accV[mt] = __builtin_amdgcn_mfma_f32_16x16x32_bf16(ah8, bl8, accV[mt], 0, 0, 0);
                accV[mt] = __builtin_amdgcn_mfma_f32_16x16x32_bf16(al8, bh8, accV[mt], 0, 0, 0);
            }
        }
    }

    // epilogue: loc + per-row LN sums (verified R4 pattern)
    const int n = n0 + w * 16 + r16;
    #pragma unroll
    for (int mt = 0; mt < 4; ++mt) {
        #pragma unroll
        for (int i = 0; i < 4; ++i) {
            const int m = m0 + mt * 16 + quad * 4 + i;
            loc[((size_t)(b * L_ + m)) * 512 + n] = accV[mt][i];
            float s = accV[mt][i], s2 = s * s;
            #pragma unroll
            for (int off = 8; off > 0; off >>= 1) {
                s  += __shfl_xor(s, off, 16);
                s2 += __shfl_xor(s2, off, 16);
            }
            if (r16 == 0) {
                redS[w][mt * 16 + quad * 4 + i] = s;
                redQ[w][mt * 16 + quad * 4 + i] = s2;
            }
        }
    }
    __syncthreads();
    if (tid < 64)
        atomicAdd(&rowsum[(size_t)b * L_ + m0 + tid],
                  redS[0][tid] + redS[1][tid] + redS[2][tid] + redS[3][tid]);
    else if (tid < 128) {
        const int t = tid - 64;
        atomicAdd(&rowsum[2048 + (size_t)b * L_ + m0 + t],
                  redQ[0][t] + redQ[1][t] + redQ[2][t] + redQ[3][t]);
    }
}

// ---------------- out GEMM + inline LayerNorm (A: normalize; B: prepped bf16 int4) ----------------
__global__ __launch_bounds__(256) void k_gemm_out2(
    const float* __restrict__ loc, const float* __restrict__ rowsum,
    const unsigned short* __restrict__ OWt,   // W[896:1408] bf16 n-major [512][512]
    const float* __restrict__ lng, const float* __restrict__ lnb,
    const float* __restrict__ bias, const float* __restrict__ resid,
    float* __restrict__ out)
{
    __shared__ unsigned short As[64 * 32];
    __shared__ unsigned short Bs[64 * 32];
    __shared__ float muS[64], rsS[64], nfiS[64];
    __shared__ float lgS[512], lbS[512];
    const int tid = threadIdx.x;
    const int w = tid >> 6;
    const int lane = tid & 63;
    const int m0 = blockIdx.y * 64;
    const int n0 = blockIdx.x * 64;
    const int srow = tid >> 2;
    const int scol = (tid & 3) * 8;
    const int quad = lane >> 4, r16 = lane & 15;

    if (tid < 64) {
        const int m = m0 + tid;
        const int l = m & (L_ - 1);
        float nf = sqrtf(4.0f * (float)(l + 1));
        float rs = rowsum[m], rq = rowsum[2048 + m];
        float mu = rs / (nf * 512.0f);
        float ey2 = rq / (nf * nf * 512.0f);
        float var = ey2 - mu * mu;
        muS[tid] = mu;
        rsS[tid] = rsqrtf(var + 1e-5f);
        nfiS[tid] = 1.0f / nf;
    }
    lgS[tid] = lng[tid];       lgS[256 + tid] = lng[256 + tid];
    lbS[tid] = lnb[tid];       lbS[256 + tid] = lnb[256 + tid];
    __syncthreads();

    f32x4 acc[4];
    #pragma unroll
    for (int mt = 0; mt < 4; ++mt) acc[mt] = (f32x4){0.f, 0.f, 0.f, 0.f};

    const float* ap = loc + (size_t)(m0 + srow) * 512 + scol;
    const unsigned short* bp = OWt + (size_t)(n0 + srow) * 512 + scol;

    for (int k0 = 0; k0 < 512; k0 += 32) {
        float4 f0 = *(const float4*)(ap + k0);
        float4 f1 = *(const float4*)(ap + k0 + 4);
        int4 bv = *(const int4*)(bp + k0);
        const float mu = muS[srow], rstd = rsS[srow], nfi = nfiS[srow];
        float yv[8];
        yv[0] = f0.x; yv[1] = f0.y; yv[2] = f0.z; yv[3] = f0.w;
        yv[4] = f1.x; yv[5] = f1.y; yv[6] = f1.z; yv[7] = f1.w;
        unsigned short avs[8];
        #pragma unroll
        for (int j = 0; j < 8; ++j) {
            float yn = (yv[j] * nfi - mu) * rstd * lgS[k0 + scol + j] + lbS[k0 + scol + j];
            avs[j] = f2bf(yn);
        }
        __syncthreads();
        *(int4*)&As[srow * 32 + scol] = *(int4*)avs;
        *(int4*)&Bs[srow * 32 + scol] = bv;
        __syncthreads();
        bf16x8 bfr = *(const bf16x8*)&Bs[(w * 16 + r16) * 32 + quad * 8];
        #pragma unroll
        for (int mt = 0; mt < 4; ++mt) {
            bf16x8 af = *(const bf16x8*)&As[(mt * 16 + r16) * 32 + quad * 8];
            acc[mt] = __builtin_amdgcn_mfma_f32_16x16x32_bf16(af, bfr, acc[mt], 0, 0, 0);
        }
    }
    const int n = n0 + w * 16 + r16;
    const float bn = bias[n];
    #pragma unroll
    for (int mt = 0; mt < 4; ++mt) {
        #pragma unroll
        for (int i = 0; i < 4; ++i) {
            const int m = m0 + mt * 16 + quad * 4 + i;
            out[(size_t)m * 512 + n] = acc[mt][i] + bn + resid[(size_t)m * 512 + n];
        }
    }
}

extern "C" void kernel_launch(void* const* d_in, const int* in_sizes, int n_in,
                              void* d_out, int out_size, void* d_ws, size_t ws_size,
                              hipStream_t stream)
{
    const float* x      = (const float*)d_in[0];
    const float* keyw   = (const float*)d_in[1];
    const float* qryw   = (const float*)d_in[2];
    const float* vw     = (const float*)d_in[4];
    const float* vb     = (const float*)d_in[5];
    const float* lng    = (const float*)d_in[6];
    const float* lnb    = (const float*)d_in[7];
    const float* outw   = (const float*)d_in[8];
    const float* outb   = (const float*)d_in[9];
    const float* setw   = (const float*)d_in[10];
    const float* pf     = (const float*)d_in[11];
    const float* posw   = (const float*)d_in[12];
    const float* g1w    = (const float*)d_in[13];
    const float* g1b    = (const float*)d_in[14];
    const float* g2w    = (const float*)d_in[15];
    const float* g2b    = (const float*)d_in[16];
    const float* sscale = (const float*)d_in[19];
    const float* sbias  = (const float*)d_in[20];
    const float* rscale = (const float*)d_in[21];
    const float* rthr   = (const float*)d_in[22];

    char* wsb = (char*)d_ws;
    float*          R      = (float*)(wsb + 0);            // 2.25 MiB
    float*          scal   = (float*)(wsb + 2359296);      // 1 MiB
    float*          loc    = (float*)(wsb + 3407872);      // 4 MiB
    unsigned short* W      = (unsigned short*)(wsb + 7602176);   // 1.375 MiB
    unsigned short* Vthi   = (unsigned short*)(wsb + 9043968);   // 2 MiB
    unsigned short* Vtlo   = (unsigned short*)(wsb + 11141120);  // 2 MiB
    unsigned short* Qf     = (unsigned short*)(wsb + 13238272);  // 256 KiB
    unsigned short* Kf     = (unsigned short*)(wsb + 13500416);  // 256 KiB
    float*          gtab   = (float*)(wsb + 13762560);     // 4 KiB
    float*          rowsum = (float*)(wsb + 13766656);     // 16 KiB

    float* out = (float*)d_out;

    k_prep_w<<<176, 256, 0, stream>>>(keyw, qryw, g1w, vw, outw, W, rowsum);
    k_gemm1v<<<dim3(7, 32), 256, 0, stream>>>(x, W, g1b, vb, R, Vthi, Vtlo);
    k_phasor<<<NROW / 4, 256, 0, stream>>>(R, g2w, g2b, scal);
    k_wg2<<<B_ + 1, 1024, 0, stream>>>(scal, pf, rscale, rthr, sscale, sbias,
                                       setw, gtab, Qf, Kf);
    k_avF<<<256, 256, 0, stream>>>(Qf, Kf, scal, gtab, posw, Vthi, Vtlo, loc, rowsum);
    k_gemm_out2<<<dim3(8, 32), 256, 0, stream>>>(loc, rowsum, W + (size_t)896 * 512,
                                                 lng, lnb, outb, x, out);
}

// Round 6
// 212.274 us; speedup vs baseline: 1.0591x; 1.0591x over previous
//
#include <hip/hip_runtime.h>
#include <math.h>

#define B_ 2
#define L_ 1024
#define D_ 512
#define NROW 2048
#define RS 288                  // R stride: key16|query16|g1 256
#define PI_F 3.14159274f
#define TWO_PI_F 6.28318548f

typedef __attribute__((ext_vector_type(8))) short bf16x8;
typedef __attribute__((ext_vector_type(4))) float f32x4;

__device__ __forceinline__ unsigned short f2bf(float f) {
    unsigned u = __float_as_uint(f);
    unsigned r = (u + 0x7FFFu + ((u >> 16) & 1u)) >> 16;
    return (unsigned short)r;
}
__device__ __forceinline__ float bf2f(unsigned short h) {
    return __uint_as_float((unsigned)h << 16);
}
__device__ __forceinline__ unsigned pack2(float a, float b) {
    return (unsigned)f2bf(a) | ((unsigned)f2bf(b) << 16);
}

// ---------------- weight prep: tiled transpose + bf16 cast (verified R1) ----------------
__global__ __launch_bounds__(256) void k_prep_w(
    const float* __restrict__ keyw, const float* __restrict__ qryw,
    const float* __restrict__ g1w, const float* __restrict__ vw,
    const float* __restrict__ outw, unsigned short* __restrict__ W)
{
    const int nt = blockIdx.x % 22;
    const int kt = blockIdx.x / 22;     // 0..7
    const int n0 = nt * 64, k0 = kt * 64;
    __shared__ unsigned short tile[64 * 68];   // [k][n], stride 68
    const int tn = threadIdx.x & 63;
    const int tk4 = threadIdx.x >> 6;   // 0..3
    const int n = n0 + tn;
    const float* src = nullptr; int stride = 0, col = 0;
    if (n < 16)        { src = keyw; stride = 16;  col = n; }
    else if (n < 32)   { src = qryw; stride = 16;  col = n - 16; }
    else if (n < 288)  { src = g1w;  stride = 256; col = n - 32; }
    else if (n < 800)  { src = vw;   stride = 512; col = n - 288; }
    else if (n < 896)  { src = nullptr; }
    else               { src = outw; stride = 512; col = n - 896; }
    #pragma unroll
    for (int r = 0; r < 16; ++r) {
        int k = k0 + tk4 * 16 + r;
        float v = src ? src[(size_t)k * stride + col] : 0.f;
        tile[(tk4 * 16 + r) * 68 + tn] = f2bf(v);
    }
    __syncthreads();
    #pragma unroll
    for (int r = 0; r < 16; ++r) {
        int nn = n0 + tk4 * 16 + r;
        W[(size_t)nn * 512 + k0 + tn] = tile[tn * 68 + tk4 * 16 + r];
    }
}

// ---------------- GEMM1: R[2048][288] (k/q/g1) + Vt hi/lo (V region) (verified R5) ----------------
__global__ __launch_bounds__(256) void k_gemm1v(
    const float* __restrict__ x,
    const unsigned short* __restrict__ Bt,   // W[0:896][512] bf16 n-major
    const float* __restrict__ g1b, const float* __restrict__ vb,
    float* __restrict__ R,
    unsigned short* __restrict__ Vthi, unsigned short* __restrict__ Vtlo)
{
    __shared__ unsigned short As[64 * 32];
    __shared__ unsigned short Bs[128 * 32];
    const int tid = threadIdx.x;
    const int w = tid >> 6;
    const int lane = tid & 63;
    const int m0 = blockIdx.y * 64;
    const int n0 = blockIdx.x * 128;
    const int srow = tid >> 2;
    const int scol = (tid & 3) * 8;
    const int quad = lane >> 4, r16 = lane & 15;

    f32x4 acc[4][2];
    #pragma unroll
    for (int mt = 0; mt < 4; ++mt)
        #pragma unroll
        for (int nt = 0; nt < 2; ++nt)
            acc[mt][nt] = (f32x4){0.f, 0.f, 0.f, 0.f};

    const float* ap = x + (size_t)(m0 + srow) * 512 + scol;
    const unsigned short* bp0 = Bt + (size_t)(n0 + srow) * 512 + scol;
    const unsigned short* bp1 = Bt + (size_t)(n0 + 64 + srow) * 512 + scol;

    for (int k0 = 0; k0 < 512; k0 += 32) {
        float4 a0 = *(const float4*)(ap + k0);
        float4 a1 = *(const float4*)(ap + k0 + 4);
        int4 bv0 = *(const int4*)(bp0 + k0);
        int4 bv1 = *(const int4*)(bp1 + k0);
        int4 av;
        av.x = (int)f2bf(a0.x) | ((int)f2bf(a0.y) << 16);
        av.y = (int)f2bf(a0.z) | ((int)f2bf(a0.w) << 16);
        av.z = (int)f2bf(a1.x) | ((int)f2bf(a1.y) << 16);
        av.w = (int)f2bf(a1.z) | ((int)f2bf(a1.w) << 16);
        __syncthreads();
        *(int4*)&As[srow * 32 + scol] = av;
        *(int4*)&Bs[srow * 32 + scol] = bv0;
        *(int4*)&Bs[(64 + srow) * 32 + scol] = bv1;
        __syncthreads();
        bf16x8 af[4], bfr[2];
        #pragma unroll
        for (int mt = 0; mt < 4; ++mt)
            af[mt] = *(const bf16x8*)&As[(mt * 16 + r16) * 32 + quad * 8];
        #pragma unroll
        for (int nt = 0; nt < 2; ++nt)
            bfr[nt] = *(const bf16x8*)&Bs[(w * 32 + nt * 16 + r16) * 32 + quad * 8];
        #pragma unroll
        for (int mt = 0; mt < 4; ++mt)
            #pragma unroll
            for (int nt = 0; nt < 2; ++nt)
                acc[mt][nt] = __builtin_amdgcn_mfma_f32_16x16x32_bf16(
                    af[mt], bfr[nt], acc[mt][nt], 0, 0, 0);
    }

    #pragma unroll
    for (int mt = 0; mt < 4; ++mt) {
        #pragma unroll
        for (int nt = 0; nt < 2; ++nt) {
            const int n = n0 + w * 32 + nt * 16 + r16;
            if (n < 288) {
                float bias = (n >= 32) ? g1b[n - 32] : 0.f;
                #pragma unroll
                for (int i = 0; i < 4; ++i) {
                    const int m = m0 + mt * 16 + quad * 4 + i;
                    R[(size_t)m * RS + n] = acc[mt][nt][i] + bias;
                }
            } else if (n < 800) {
                const int d = n - 288;
                const float bias = vb[d];
                ushort4 h4, l4;
                #pragma unroll
                for (int i = 0; i < 4; ++i) {
                    float v = acc[mt][nt][i] + bias;
                    unsigned short hi = f2bf(v);
                    ((unsigned short*)&h4)[i] = hi;
                    ((unsigned short*)&l4)[i] = f2bf(v - bf2f(hi));
                }
                const size_t vo = (size_t)d * 2048 + m0 + mt * 16 + quad * 4;
                *(ushort4*)&Vthi[vo] = h4;
                *(ushort4*)&Vtlo[vo] = l4;
            }
        }
    }
}

// ---------------- phasors, jk/jq, gate (verified) ----------------
__global__ __launch_bounds__(256) void k_phasor(
    const float* __restrict__ R,
    const float* __restrict__ g2w, const float* __restrict__ g2b,
    float* __restrict__ scal)
{
    const int row = blockIdx.x * 4 + (threadIdx.x >> 6);
    const int lane = threadIdx.x & 63;
    float* sc = scal + (size_t)row * 128;
    const float* r = R + (size_t)row * RS;

    float part = 0.f;
    #pragma unroll
    for (int j = 0; j < 4; ++j) {
        float v = r[32 + lane * 4 + j];
        float h = 0.5f * v * (1.0f + erff(v * 0.70710678f));
        part += h * g2w[lane * 4 + j];
    }
    #pragma unroll
    for (int off = 32; off > 0; off >>= 1) part += __shfl_down(part, off, 64);
    if (lane == 0) sc[112] = 1.0f / (1.0f + expf(-(part + g2b[0])));

    float pr = 1.f, pim = 0.f;
    if (lane < 32) {
        float a = tanhf(r[lane]) * PI_F;
        float sv, cv;
        sincosf(a, &sv, &cv);
        int t = lane & 15;
        if (lane < 16) { sc[t] = cv; sc[16 + t] = sv; }
        else           { sc[32 + t] = cv; sc[48 + t] = sv; }
        pr = cv; pim = sv;
    }
    #pragma unroll
    for (int m = 4; m <= 8; m <<= 1) {
        float orr = __shfl_xor(pr, m, 64);
        float oii = __shfl_xor(pim, m, 64);
        float nr = pr * orr - pim * oii;
        float ni = pr * oii + pim * orr;
        pr = nr; pim = ni;
    }
    if (lane < 4)                     { sc[64 + lane] = pr; sc[68 + lane] = pim; }
    else if (lane >= 16 && lane < 20) { sc[72 + lane - 16] = pr; sc[76 + lane - 16] = pim; }
}

// ---------------- wg scan + surprise gate + Qf/Kf build + gtab (verified R4/R5) ----------------
__global__ __launch_bounds__(1024) void k_wg2(
    const float* __restrict__ scal, const float* __restrict__ pf,
    const float* __restrict__ res_scale, const float* __restrict__ res_thr,
    const float* __restrict__ sur_scale, const float* __restrict__ sur_bias,
    const float* __restrict__ setw,
    float* __restrict__ gtab,
    unsigned short* __restrict__ Qf, unsigned short* __restrict__ Kf)
{
    const int b = blockIdx.x;
    const int l = threadIdx.x;
    if (b == B_) {
        float g = 0.f;
        #pragma unroll
        for (int p = 0; p < 16; ++p)
            g += cosf(TWO_PI_F * (float)l * pf[p]);
        gtab[l] = g;
        return;
    }
    const size_t row = (size_t)(b * L_ + l) * 128;
    float v[8], own[8];
    #pragma unroll
    for (int c2 = 0; c2 < 8; ++c2) { v[c2] = scal[row + 64 + c2]; own[c2] = v[c2]; }
    const int lane = l & 63;
    const int wave = l >> 6;
    #pragma unroll
    for (int off = 1; off < 64; off <<= 1) {
        float o[8];
        #pragma unroll
        for (int c2 = 0; c2 < 8; ++c2) o[c2] = __shfl_up(v[c2], off, 64);
        if (lane >= off) {
            #pragma unroll
            for (int c2 = 0; c2 < 8; ++c2) v[c2] += o[c2];
        }
    }
    __shared__ float wtot[16][8];
    if (lane == 63) {
        #pragma unroll
        for (int c2 = 0; c2 < 8; ++c2) wtot[wave][c2] = v[c2];
    }
    __syncthreads();
    float pre[8] = {0,0,0,0,0,0,0,0};
    for (int w2 = 0; w2 < wave; ++w2) {
        #pragma unroll
        for (int c2 = 0; c2 < 8; ++c2) pre[c2] += wtot[w2][c2];
    }
    float km[8];
    #pragma unroll
    for (int c2 = 0; c2 < 8; ++c2) km[c2] = pre[c2] + v[c2] - own[c2];
    float mag = 0.f;
    #pragma unroll
    for (int pp = 0; pp < 4; ++pp) {
        float jqr = scal[row + 72 + pp], jqi = scal[row + 76 + pp];
        float re = km[pp] * jqr + km[4 + pp] * jqi;
        float im = km[4 + pp] * jqr - km[pp] * jqi;
        mag += sqrtf(re * re + im * im);
    }
    mag *= 0.25f;
    float posn = fmaxf((float)l, 1.0f);
    float nres = mag / sqrtf(posn);
    float scl = fminf(fmaxf(res_scale[0], 1.0f), 20.0f);
    float thr = fminf(fmaxf(res_thr[0], 0.1f), 0.9f);
    float sur = 0.5f * (1.0f - tanhf(scl * (nres - thr)));
    float wgv = 1.0f / (1.0f + expf(-(sur_scale[0] * (sur - 0.5f) + sur_bias[0])));

    const float gate = scal[row + 112];
    float s0 = setw[0], s1 = setw[1], s2 = setw[2], s3 = setw[3];
    float mx = fmaxf(fmaxf(s0, s1), fmaxf(s2, s3));
    float e0 = expf(s0 - mx), e1 = expf(s1 - mx), e2 = expf(s2 - mx), e3 = expf(s3 - mx);
    float esum = e0 + e1 + e2 + e3;
    float w4[4] = {e0 / esum, e1 / esum, e2 / esum, e3 / esum};
    const float qs = 0.2f * gate;

    unsigned* qp = (unsigned*)(Qf + (size_t)(b * L_ + l) * 64);
    unsigned* kp = (unsigned*)(Kf + (size_t)(b * L_ + l) * 64);
    #pragma unroll
    for (int s = 0; s < 16; ++s) {
        float wgrp = w4[s >> 2];
        qp[s] = pack2(qs * wgrp * scal[row + 32 + s], qs * wgrp * scal[row + 48 + s]);
        kp[s] = pack2(wgv * scal[row + s], wgv * scal[row + 16 + s]);
    }
    #pragma unroll
    for (int p = 0; p < 4; ++p) {
        qp[16 + p] = pack2(qs * scal[row + 72 + p], qs * scal[row + 76 + p]);
        kp[16 + p] = pack2(wgv * scal[row + 64 + p], wgv * scal[row + 68 + p]);
    }
    #pragma unroll
    for (int s = 20; s < 32; ++s) { qp[s] = 0u; kp[s] = 0u; }
}

// ---------------- split-k fused A-build + AV: Q/K/V frags direct from global, A via LDS ----------------
// block = (b, ti, nj, h). h-half of tj range; partial results to part[h].
__global__ __launch_bounds__(256) void k_avS(
    const unsigned short* __restrict__ Qf, const unsigned short* __restrict__ Kf,
    const float* __restrict__ scal, const float* __restrict__ gtab,
    const float* __restrict__ posw,
    const unsigned short* __restrict__ Vthi, const unsigned short* __restrict__ Vtlo,
    float* __restrict__ parts)
{
    const int bx = blockIdx.x;             // ((b*16+ti)*8+nj)*2+h = 512
    const int h  = bx & 1;
    const int nj = (bx >> 1) & 7;
    const int ti = (bx >> 4) & 15;
    const int b  = bx >> 8;
    const int m0 = ti * 64, n0 = nj * 64;
    float* prt = parts + (size_t)h * NROW * 512;

    const int tid = threadIdx.x;
    const int w = tid >> 6, lane = tid & 63;
    const int quad = lane >> 4, r16 = lane & 15;

    const int nh = (ti + 2) >> 1;          // balanced split
    const int tj0 = h ? nh : 0;
    const int tj1 = h ? (ti + 1) : nh;

    if (tj0 >= tj1) {                       // only ti=0,h=1: write zeros
        f32x4 z = (f32x4){0.f, 0.f, 0.f, 0.f};
        #pragma unroll
        for (int mt = 0; mt < 4; ++mt)
            #pragma unroll
            for (int i = 0; i < 4; ++i)
                *(f32x4*)&prt[((size_t)(b * L_ + m0 + mt * 16 + quad * 4 + i)) * 512
                              + n0 + w * 16 + (r16 & 12)] = z;
        // note: 4 lanes of each 16-group write same addr group; harmless dup zeros
        return;
    }

    __shared__ unsigned short Ah[64 * 68];
    __shared__ unsigned short Al[64 * 68];
    __shared__ float gS[64];

    // Q fragments in registers (row = m0+mt*16+r16, k = kk*32+quad*8)
    bf16x8 qf[2][4];
    #pragma unroll
    for (int kk = 0; kk < 2; ++kk)
        #pragma unroll
        for (int mt = 0; mt < 4; ++mt)
            qf[kk][mt] = *(const bf16x8*)(Qf +
                ((size_t)(b * L_ + m0 + mt * 16 + r16)) * 64 + kk * 32 + quad * 8);
    if (tid < 64) gS[tid] = scal[((size_t)(b * L_ + m0 + tid)) * 128 + 112];
    const float sw = 1.0f / (1.0f + expf(-posw[0]));

    // K fragments for first tj (col = tj*64 + w*16 + r16, k = kk*32 + quad*8)
    bf16x8 kf0, kf1;
    {
        const size_t kb = ((size_t)(b * L_ + tj0 * 64 + w * 16 + r16)) * 64 + quad * 8;
        kf0 = *(const bf16x8*)(Kf + kb);
        kf1 = *(const bf16x8*)(Kf + kb + 32);
    }

    f32x4 accV[4];
    #pragma unroll
    for (int mt = 0; mt < 4; ++mt) accV[mt] = (f32x4){0.f, 0.f, 0.f, 0.f};

    for (int tj = tj0; tj < tj1; ++tj) {
        // issue V loads (consumed after A-pack; hidden under QK+pack)
        const size_t vb0 = (size_t)(n0 + w * 16 + r16) * 2048 + b * L_ + tj * 64 + quad * 8;
        bf16x8 vh0 = *(const bf16x8*)(Vthi + vb0);
        bf16x8 vh1 = *(const bf16x8*)(Vthi + vb0 + 32);
        bf16x8 vl0 = *(const bf16x8*)(Vtlo + vb0);
        bf16x8 vl1 = *(const bf16x8*)(Vtlo + vb0 + 32);

        // QK^T
        f32x4 a4[4];
        #pragma unroll
        for (int mt = 0; mt < 4; ++mt) a4[mt] = (f32x4){0.f, 0.f, 0.f, 0.f};
        #pragma unroll
        for (int mt = 0; mt < 4; ++mt) {
            a4[mt] = __builtin_amdgcn_mfma_f32_16x16x32_bf16(qf[0][mt], kf0, a4[mt], 0, 0, 0);
            a4[mt] = __builtin_amdgcn_mfma_f32_16x16x32_bf16(qf[1][mt], kf1, a4[mt], 0, 0, 0);
        }
        // prefetch next K
        if (tj + 1 < tj1) {
            const size_t kb = ((size_t)(b * L_ + (tj + 1) * 64 + w * 16 + r16)) * 64 + quad * 8;
            kf0 = *(const bf16x8*)(Kf + kb);
            kf1 = *(const bf16x8*)(Kf + kb + 32);
        }

        __syncthreads();   // previous AV reads of Ah/Al done (first iter: covers gS)
        const int lp = tj * 64 + w * 16 + r16;
        #pragma unroll
        for (int mt = 0; mt < 4; ++mt) {
            #pragma unroll
            for (int i = 0; i < 4; ++i) {
                const int lr = mt * 16 + quad * 4 + i;
                const int dl = (m0 + lr) - lp;
                float v = 0.f;
                if (dl >= 0)
                    v = a4[mt][i] + (1.0f - gS[lr]) * sw * gtab[dl];
                unsigned short hi = f2bf(v);
                Ah[lr * 68 + w * 16 + r16] = hi;
                Al[lr * 68 + w * 16 + r16] = f2bf(v - bf2f(hi));
            }
        }
        __syncthreads();   // A ready

        // AV (V frags arrived by now)
        #pragma unroll
        for (int mt = 0; mt < 4; ++mt) {
            bf16x8 ah0 = *(const bf16x8*)&Ah[(mt * 16 + r16) * 68 + quad * 8];
            bf16x8 al0 = *(const bf16x8*)&Al[(mt * 16 + r16) * 68 + quad * 8];
            bf16x8 ah1 = *(const bf16x8*)&Ah[(mt * 16 + r16) * 68 + 32 + quad * 8];
            bf16x8 al1 = *(const bf16x8*)&Al[(mt * 16 + r16) * 68 + 32 + quad * 8];
            accV[mt] = __builtin_amdgcn_mfma_f32_16x16x32_bf16(ah0, vh0, accV[mt], 0, 0, 0);
            accV[mt] = __builtin_amdgcn_mfma_f32_16x16x32_bf16(ah0, vl0, accV[mt], 0, 0, 0);
            accV[mt] = __builtin_amdgcn_mfma_f32_16x16x32_bf16(al0, vh0, accV[mt], 0, 0, 0);
            accV[mt] = __builtin_amdgcn_mfma_f32_16x16x32_bf16(ah1, vh1, accV[mt], 0, 0, 0);
            accV[mt] = __builtin_amdgcn_mfma_f32_16x16x32_bf16(ah1, vl1, accV[mt], 0, 0, 0);
            accV[mt] = __builtin_amdgcn_mfma_f32_16x16x32_bf16(al1, vh1, accV[mt], 0, 0, 0);
        }
    }

    const int n = n0 + w * 16 + r16;
    #pragma unroll
    for (int mt = 0; mt < 4; ++mt)
        #pragma unroll
        for (int i = 0; i < 4; ++i)
            prt[((size_t)(b * L_ + m0 + mt * 16 + quad * 4 + i)) * 512 + n] = accV[mt][i];
}

// ---------------- combine parts -> LN row sums ----------------
__global__ __launch_bounds__(256) void k_rs(
    const float* __restrict__ parts, float* __restrict__ rowsum)
{
    const int wv = threadIdx.x >> 6, lane = threadIdx.x & 63;
    #pragma unroll
    for (int rep = 0; rep < 2; ++rep) {
        const int row = blockIdx.x * 8 + wv * 2 + rep;
        const float* p0 = parts + (size_t)row * 512 + lane * 8;
        const float* p1 = p0 + (size_t)NROW * 512;
        float4 a0 = *(const float4*)p0,       a1 = *(const float4*)(p0 + 4);
        float4 b0 = *(const float4*)p1,       b1 = *(const float4*)(p1 + 4);
        float s = 0.f, s2 = 0.f;
        #pragma unroll
        for (int j = 0; j < 4; ++j) {
            float y0 = ((const float*)&a0)[j] + ((const float*)&b0)[j];
            float y1 = ((const float*)&a1)[j] + ((const float*)&b1)[j];
            s += y0 + y1; s2 += y0 * y0 + y1 * y1;
        }
        #pragma unroll
        for (int off = 32; off > 0; off >>= 1) {
            s  += __shfl_down(s, off, 64);
            s2 += __shfl_down(s2, off, 64);
        }
        if (lane == 0) { rowsum[row] = s; rowsum[2048 + row] = s2; }
    }
}

// ---------------- out GEMM + inline LayerNorm (A = part0+part1 normalized; B prepped bf16) ----------------
__global__ __launch_bounds__(256) void k_gemm_out2(
    const float* __restrict__ parts, const float* __restrict__ rowsum,
    const unsigned short* __restrict__ OWt,
    const float* __restrict__ lng, const float* __restrict__ lnb,
    const float* __restrict__ bias, const float* __restrict__ resid,
    float* __restrict__ out)
{
    __shared__ unsigned short As[64 * 32];
    __shared__ unsigned short Bs[64 * 32];
    __shared__ float muS[64], rsS[64], nfiS[64];
    __shared__ float lgS[512], lbS[512];
    const int tid = threadIdx.x;
    const int w = tid >> 6;
    const int lane = tid & 63;
    const int m0 = blockIdx.y * 64;
    const int n0 = blockIdx.x * 64;
    const int srow = tid >> 2;
    const int scol = (tid & 3) * 8;
    const int quad = lane >> 4, r16 = lane & 15;

    if (tid < 64) {
        const int m = m0 + tid;
        const int l = m & (L_ - 1);
        float nf = sqrtf(4.0f * (float)(l + 1));
        float rs = rowsum[m], rq = rowsum[2048 + m];
        float mu = rs / (nf * 512.0f);
        float ey2 = rq / (nf * nf * 512.0f);
        float var = ey2 - mu * mu;
        muS[tid] = mu;
        rsS[tid] = rsqrtf(var + 1e-5f);
        nfiS[tid] = 1.0f / nf;
    }
    lgS[tid] = lng[tid];       lgS[256 + tid] = lng[256 + tid];
    lbS[tid] = lnb[tid];       lbS[256 + tid] = lnb[256 + tid];
    __syncthreads();

    f32x4 acc[4];
    #pragma unroll
    for (int mt = 0; mt < 4; ++mt) acc[mt] = (f32x4){0.f, 0.f, 0.f, 0.f};

    const float* ap0 = parts + (size_t)(m0 + srow) * 512 + scol;
    const float* ap1 = ap0 + (size_t)NROW * 512;
    const unsigned short* bp = OWt + (size_t)(n0 + srow) * 512 + scol;

    for (int k0 = 0; k0 < 512; k0 += 32) {
        float4 f0 = *(const float4*)(ap0 + k0);
        float4 f1 = *(const float4*)(ap0 + k0 + 4);
        float4 g0 = *(const float4*)(ap1 + k0);
        float4 g1 = *(const float4*)(ap1 + k0 + 4);
        int4 bv = *(const int4*)(bp + k0);
        const float mu = muS[srow], rstd = rsS[srow], nfi = nfiS[srow];
        float yv[8];
        yv[0] = f0.x + g0.x; yv[1] = f0.y + g0.y; yv[2] = f0.z + g0.z; yv[3] = f0.w + g0.w;
        yv[4] = f1.x + g1.x; yv[5] = f1.y + g1.y; yv[6] = f1.z + g1.z; yv[7] = f1.w + g1.w;
        unsigned short avs[8];
        #pragma unroll
        for (int j = 0; j < 8; ++j) {
            float yn = (yv[j] * nfi - mu) * rstd * lgS[k0 + scol + j] + lbS[k0 + scol + j];
            avs[j] = f2bf(yn);
        }
        __syncthreads();
        *(int4*)&As[srow * 32 + scol] = *(int4*)avs;
        *(int4*)&Bs[srow * 32 + scol] = bv;
        __syncthreads();
        bf16x8 bfr = *(const bf16x8*)&Bs[(w * 16 + r16) * 32 + quad * 8];
        #pragma unroll
        for (int mt = 0; mt < 4; ++mt) {
            bf16x8 af = *(const bf16x8*)&As[(mt * 16 + r16) * 32 + quad * 8];
            acc[mt] = __builtin_amdgcn_mfma_f32_16x16x32_bf16(af, bfr, acc[mt], 0, 0, 0);
        }
    }
    const int n = n0 + w * 16 + r16;
    const float bn = bias[n];
    #pragma unroll
    for (int mt = 0; mt < 4; ++mt) {
        #pragma unroll
        for (int i = 0; i < 4; ++i) {
            const int m = m0 + mt * 16 + quad * 4 + i;
            out[(size_t)m * 512 + n] = acc[mt][i] + bn + resid[(size_t)m * 512 + n];
        }
    }
}

extern "C" void kernel_launch(void* const* d_in, const int* in_sizes, int n_in,
                              void* d_out, int out_size, void* d_ws, size_t ws_size,
                              hipStream_t stream)
{
    const float* x      = (const float*)d_in[0];
    const float* keyw   = (const float*)d_in[1];
    const float* qryw   = (const float*)d_in[2];
    const float* vw     = (const float*)d_in[4];
    const float* vb     = (const float*)d_in[5];
    const float* lng    = (const float*)d_in[6];
    const float* lnb    = (const float*)d_in[7];
    const float* outw   = (const float*)d_in[8];
    const float* outb   = (const float*)d_in[9];
    const float* setw   = (const float*)d_in[10];
    const float* pf     = (const float*)d_in[11];
    const float* posw   = (const float*)d_in[12];
    const float* g1w    = (const float*)d_in[13];
    const float* g1b    = (const float*)d_in[14];
    const float* g2w    = (const float*)d_in[15];
    const float* g2b    = (const float*)d_in[16];
    const float* sscale = (const float*)d_in[19];
    const float* sbias  = (const float*)d_in[20];
    const float* rscale = (const float*)d_in[21];
    const float* rthr   = (const float*)d_in[22];

    char* wsb = (char*)d_ws;
    float*          R      = (float*)(wsb + 0);                  // 2.25 MiB
    float*          scal   = (float*)(wsb + 2359296);            // 1 MiB
    float*          parts  = (float*)(wsb + 3407872);            // 8 MiB (2 slots)
    unsigned short* W      = (unsigned short*)(wsb + 11796480);  // 1.375 MiB
    unsigned short* Vthi   = (unsigned short*)(wsb + 13238272);  // 2 MiB
    unsigned short* Vtlo   = (unsigned short*)(wsb + 15335424);  // 2 MiB
    unsigned short* Qf     = (unsigned short*)(wsb + 17432576);  // 256 KiB
    unsigned short* Kf     = (unsigned short*)(wsb + 17694720);  // 256 KiB
    float*          gtab   = (float*)(wsb + 17956864);           // 4 KiB
    float*          rowsum = (float*)(wsb + 17960960);           // 16 KiB

    float* out = (float*)d_out;

    k_prep_w<<<176, 256, 0, stream>>>(keyw, qryw, g1w, vw, outw, W);
    k_gemm1v<<<dim3(7, 32), 256, 0, stream>>>(x, W, g1b, vb, R, Vthi, Vtlo);
    k_phasor<<<NROW / 4, 256, 0, stream>>>(R, g2w, g2b, scal);
    k_wg2<<<B_ + 1, 1024, 0, stream>>>(scal, pf, rscale, rthr, sscale, sbias,
                                       setw, gtab, Qf, Kf);
    k_avS<<<512, 256, 0, stream>>>(Qf, Kf, scal, gtab, posw, Vthi, Vtlo, parts);
    k_rs<<<256, 256, 0, stream>>>(parts, rowsum);
    k_gemm_out2<<<dim3(8, 32), 256, 0, stream>>>(parts, rowsum, W + (size_t)896 * 512,
                                                 lng, lnb, outb, x, out);
}

// Round 7
// 204.956 us; speedup vs baseline: 1.0969x; 1.0357x over previous
//
#include <hip/hip_runtime.h>
#include <math.h>

#define B_ 2
#define L_ 1024
#define D_ 512
#define NROW 2048
#define RS 288                  // R stride: key16|query16|g1 256
#define PI_F 3.14159274f
#define TWO_PI_F 6.28318548f

typedef __attribute__((ext_vector_type(8))) short bf16x8;
typedef __attribute__((ext_vector_type(4))) float f32x4;

__device__ __forceinline__ unsigned short f2bf(float f) {
    unsigned u = __float_as_uint(f);
    unsigned r = (u + 0x7FFFu + ((u >> 16) & 1u)) >> 16;
    return (unsigned short)r;
}
__device__ __forceinline__ float bf2f(unsigned short h) {
    return __uint_as_float((unsigned)h << 16);
}
__device__ __forceinline__ unsigned pack2(float a, float b) {
    return (unsigned)f2bf(a) | ((unsigned)f2bf(b) << 16);
}

// ---------------- weight prep: tiled transpose + bf16 cast (verified R1) ----------------
__global__ __launch_bounds__(256) void k_prep_w(
    const float* __restrict__ keyw, const float* __restrict__ qryw,
    const float* __restrict__ g1w, const float* __restrict__ vw,
    const float* __restrict__ outw, unsigned short* __restrict__ W)
{
    const int nt = blockIdx.x % 22;
    const int kt = blockIdx.x / 22;
    const int n0 = nt * 64, k0 = kt * 64;
    __shared__ unsigned short tile[64 * 68];
    const int tn = threadIdx.x & 63;
    const int tk4 = threadIdx.x >> 6;
    const int n = n0 + tn;
    const float* src = nullptr; int stride = 0, col = 0;
    if (n < 16)        { src = keyw; stride = 16;  col = n; }
    else if (n < 32)   { src = qryw; stride = 16;  col = n - 16; }
    else if (n < 288)  { src = g1w;  stride = 256; col = n - 32; }
    else if (n < 800)  { src = vw;   stride = 512; col = n - 288; }
    else if (n < 896)  { src = nullptr; }
    else               { src = outw; stride = 512; col = n - 896; }
    #pragma unroll
    for (int r = 0; r < 16; ++r) {
        int k = k0 + tk4 * 16 + r;
        float v = src ? src[(size_t)k * stride + col] : 0.f;
        tile[(tk4 * 16 + r) * 68 + tn] = f2bf(v);
    }
    __syncthreads();
    #pragma unroll
    for (int r = 0; r < 16; ++r) {
        int nn = n0 + tk4 * 16 + r;
        W[(size_t)nn * 512 + k0 + tn] = tile[tn * 68 + tk4 * 16 + r];
    }
}

// ---------------- GEMM1 (64x64 tiles, 448 blocks): R + Vt hi/lo ----------------
__global__ __launch_bounds__(256) void k_gemm1v(
    const float* __restrict__ x,
    const unsigned short* __restrict__ Bt,   // W[0:896][512] bf16 n-major
    const float* __restrict__ g1b, const float* __restrict__ vb,
    float* __restrict__ R,
    unsigned short* __restrict__ Vthi, unsigned short* __restrict__ Vtlo)
{
    __shared__ unsigned short As[64 * 32];
    __shared__ unsigned short Bs[64 * 32];
    const int tid = threadIdx.x;
    const int w = tid >> 6;
    const int lane = tid & 63;
    const int m0 = blockIdx.y * 64;
    const int n0 = blockIdx.x * 64;
    const int srow = tid >> 2;
    const int scol = (tid & 3) * 8;
    const int quad = lane >> 4, r16 = lane & 15;

    f32x4 acc[4];
    #pragma unroll
    for (int mt = 0; mt < 4; ++mt) acc[mt] = (f32x4){0.f, 0.f, 0.f, 0.f};

    const float* ap = x + (size_t)(m0 + srow) * 512 + scol;
    const unsigned short* bp = Bt + (size_t)(n0 + srow) * 512 + scol;

    for (int k0 = 0; k0 < 512; k0 += 32) {
        float4 a0 = *(const float4*)(ap + k0);
        float4 a1 = *(const float4*)(ap + k0 + 4);
        int4 bv = *(const int4*)(bp + k0);
        int4 av;
        av.x = (int)f2bf(a0.x) | ((int)f2bf(a0.y) << 16);
        av.y = (int)f2bf(a0.z) | ((int)f2bf(a0.w) << 16);
        av.z = (int)f2bf(a1.x) | ((int)f2bf(a1.y) << 16);
        av.w = (int)f2bf(a1.z) | ((int)f2bf(a1.w) << 16);
        __syncthreads();
        *(int4*)&As[srow * 32 + scol] = av;
        *(int4*)&Bs[srow * 32 + scol] = bv;
        __syncthreads();
        bf16x8 bfr = *(const bf16x8*)&Bs[(w * 16 + r16) * 32 + quad * 8];
        #pragma unroll
        for (int mt = 0; mt < 4; ++mt) {
            bf16x8 af = *(const bf16x8*)&As[(mt * 16 + r16) * 32 + quad * 8];
            acc[mt] = __builtin_amdgcn_mfma_f32_16x16x32_bf16(af, bfr, acc[mt], 0, 0, 0);
        }
    }

    const int n = n0 + w * 16 + r16;
    if (n < 288) {
        const float bias = (n >= 32) ? g1b[n - 32] : 0.f;
        #pragma unroll
        for (int mt = 0; mt < 4; ++mt)
            #pragma unroll
            for (int i = 0; i < 4; ++i) {
                const int m = m0 + mt * 16 + quad * 4 + i;
                R[(size_t)m * RS + n] = acc[mt][i] + bias;
            }
    } else if (n < 800) {
        const int d = n - 288;
        const float bias = vb[d];
        #pragma unroll
        for (int mt = 0; mt < 4; ++mt) {
            ushort4 h4, l4;
            #pragma unroll
            for (int i = 0; i < 4; ++i) {
                float v = acc[mt][i] + bias;
                unsigned short hi = f2bf(v);
                ((unsigned short*)&h4)[i] = hi;
                ((unsigned short*)&l4)[i] = f2bf(v - bf2f(hi));
            }
            const size_t vo = (size_t)d * 2048 + m0 + mt * 16 + quad * 4;
            *(ushort4*)&Vthi[vo] = h4;
            *(ushort4*)&Vtlo[vo] = l4;
        }
    }
}

// ---------------- phasors, jk/jq, gate + compact jkT for the scan ----------------
__global__ __launch_bounds__(256) void k_phasor(
    const float* __restrict__ R,
    const float* __restrict__ g2w, const float* __restrict__ g2b,
    float* __restrict__ scal, float* __restrict__ jkT)
{
    const int row = blockIdx.x * 4 + (threadIdx.x >> 6);
    const int lane = threadIdx.x & 63;
    const int b = row >> 10, l = row & (L_ - 1);
    float* sc = scal + (size_t)row * 128;
    const float* r = R + (size_t)row * RS;

    float part = 0.f;
    #pragma unroll
    for (int j = 0; j < 4; ++j) {
        float v = r[32 + lane * 4 + j];
        float h = 0.5f * v * (1.0f + erff(v * 0.70710678f));
        part += h * g2w[lane * 4 + j];
    }
    #pragma unroll
    for (int off = 32; off > 0; off >>= 1) part += __shfl_down(part, off, 64);
    if (lane == 0) sc[112] = 1.0f / (1.0f + expf(-(part + g2b[0])));

    float pr = 1.f, pim = 0.f;
    if (lane < 32) {
        float a = tanhf(r[lane]) * PI_F;
        float sv, cv;
        sincosf(a, &sv, &cv);
        int t = lane & 15;
        if (lane < 16) { sc[t] = cv; sc[16 + t] = sv; }
        else           { sc[32 + t] = cv; sc[48 + t] = sv; }
        pr = cv; pim = sv;
    }
    #pragma unroll
    for (int m = 4; m <= 8; m <<= 1) {
        float orr = __shfl_xor(pr, m, 64);
        float oii = __shfl_xor(pim, m, 64);
        float nr = pr * orr - pim * oii;
        float ni = pr * oii + pim * orr;
        pr = nr; pim = ni;
    }
    if (lane < 4) {
        sc[64 + lane] = pr; sc[68 + lane] = pim;
        jkT[(size_t)(b * 8 + lane) * L_ + l]     = pr;
        jkT[(size_t)(b * 8 + 4 + lane) * L_ + l] = pim;
    } else if (lane >= 16 && lane < 20) {
        sc[72 + lane - 16] = pr; sc[76 + lane - 16] = pim;
    }
}

// ---------------- 16 parallel wave-scans (exclusive prefix) + gtab block ----------------
__global__ __launch_bounds__(64) void k_scanw(
    const float* __restrict__ jkT, const float* __restrict__ pf,
    float* __restrict__ kmT, float* __restrict__ gtab)
{
    const int bx = blockIdx.x;
    const int lane = threadIdx.x;
    if (bx == 16) {
        #pragma unroll
        for (int j = 0; j < 16; ++j) {
            const int l = j * 64 + lane;
            float g = 0.f;
            #pragma unroll
            for (int p = 0; p < 16; ++p)
                g += cosf(TWO_PI_F * (float)l * pf[p]);
            gtab[l] = g;
        }
        return;
    }
    const float* src = jkT + (size_t)bx * L_;
    float* dst = kmT + (size_t)bx * L_;
    float run = 0.f;
    for (int seg = 0; seg < 16; ++seg) {
        float own = src[seg * 64 + lane];
        float v = own;
        #pragma unroll
        for (int off = 1; off < 64; off <<= 1) {
            float o = __shfl_up(v, off, 64);
            if (lane >= off) v += o;
        }
        dst[seg * 64 + lane] = run + v - own;     // exclusive
        run += __shfl(v, 63, 64);
    }
}

// ---------------- build: mag -> surprise gate -> Qf/Kf rows (row-parallel) ----------------
__global__ __launch_bounds__(64) void k_build(
    const float* __restrict__ scal, const float* __restrict__ kmT,
    const float* __restrict__ res_scale, const float* __restrict__ res_thr,
    const float* __restrict__ sur_scale, const float* __restrict__ sur_bias,
    const float* __restrict__ setw,
    unsigned short* __restrict__ Qf, unsigned short* __restrict__ Kf)
{
    const int rowi = blockIdx.x * 64 + threadIdx.x;
    const int b = rowi >> 10, l = rowi & (L_ - 1);
    const size_t row = (size_t)rowi * 128;

    float km[8];
    #pragma unroll
    for (int c2 = 0; c2 < 8; ++c2) km[c2] = kmT[(size_t)(b * 8 + c2) * L_ + l];

    float mag = 0.f;
    #pragma unroll
    for (int pp = 0; pp < 4; ++pp) {
        float jqr = scal[row + 72 + pp], jqi = scal[row + 76 + pp];
        float re = km[pp] * jqr + km[4 + pp] * jqi;
        float im = km[4 + pp] * jqr - km[pp] * jqi;
        mag += sqrtf(re * re + im * im);
    }
    mag *= 0.25f;
    float posn = fmaxf((float)l, 1.0f);
    float nres = mag / sqrtf(posn);
    float scl = fminf(fmaxf(res_scale[0], 1.0f), 20.0f);
    float thr = fminf(fmaxf(res_thr[0], 0.1f), 0.9f);
    float sur = 0.5f * (1.0f - tanhf(scl * (nres - thr)));
    float wgv = 1.0f / (1.0f + expf(-(sur_scale[0] * (sur - 0.5f) + sur_bias[0])));

    const float gate = scal[row + 112];
    float s0 = setw[0], s1 = setw[1], s2 = setw[2], s3 = setw[3];
    float mx = fmaxf(fmaxf(s0, s1), fmaxf(s2, s3));
    float e0 = expf(s0 - mx), e1 = expf(s1 - mx), e2 = expf(s2 - mx), e3 = expf(s3 - mx);
    float esum = e0 + e1 + e2 + e3;
    float w4[4] = {e0 / esum, e1 / esum, e2 / esum, e3 / esum};
    const float qs = 0.2f * gate;

    unsigned* qp = (unsigned*)(Qf + (size_t)rowi * 64);
    unsigned* kp = (unsigned*)(Kf + (size_t)rowi * 64);
    #pragma unroll
    for (int s = 0; s < 16; ++s) {
        float wgrp = w4[s >> 2];
        qp[s] = pack2(qs * wgrp * scal[row + 32 + s], qs * wgrp * scal[row + 48 + s]);
        kp[s] = pack2(wgv * scal[row + s], wgv * scal[row + 16 + s]);
    }
    #pragma unroll
    for (int p = 0; p < 4; ++p) {
        qp[16 + p] = pack2(qs * scal[row + 72 + p], qs * scal[row + 76 + p]);
        kp[16 + p] = pack2(wgv * scal[row + 64 + p], wgv * scal[row + 68 + p]);
    }
    #pragma unroll
    for (int s = 20; s < 32; ++s) { qp[s] = 0u; kp[s] = 0u; }
}

// ---------------- balanced 2-phase split-k AV: block = (ti,nj,h); phases b=0/ti, b=1/15-ti ----------------
__global__ __launch_bounds__(256) void k_avS(
    const unsigned short* __restrict__ Qf, const unsigned short* __restrict__ Kf,
    const float* __restrict__ scal, const float* __restrict__ gtab,
    const float* __restrict__ posw,
    const unsigned short* __restrict__ Vthi, const unsigned short* __restrict__ Vtlo,
    float* __restrict__ parts)
{
    const int bx = blockIdx.x;             // 256: (ti0*8+nj)*2+h
    const int h  = bx & 1;
    const int nj = (bx >> 1) & 7;
    const int ti0 = bx >> 4;
    const int n0 = nj * 64;

    __shared__ unsigned short Ah[64 * 68];
    __shared__ unsigned short Al[64 * 68];
    __shared__ float gS[64];

    const int tid = threadIdx.x;
    const int w = tid >> 6, lane = tid & 63;
    const int quad = lane >> 4, r16 = lane & 15;
    const float sw = 1.0f / (1.0f + expf(-posw[0]));
    float* prt = parts + (size_t)h * NROW * 512;

    #pragma unroll
    for (int phase = 0; phase < 2; ++phase) {
        const int b  = phase;
        const int ti = phase ? (15 - ti0) : ti0;
        const int m0 = ti * 64;
        const int nh = (ti + 2) >> 1;
        const int tj0 = h ? nh : 0;
        const int tj1 = h ? (ti + 1) : nh;

        f32x4 accV[4];
        #pragma unroll
        for (int mt = 0; mt < 4; ++mt) accV[mt] = (f32x4){0.f, 0.f, 0.f, 0.f};

        if (tj0 < tj1) {
            // Q fragments in registers
            bf16x8 qf[2][4];
            #pragma unroll
            for (int kk = 0; kk < 2; ++kk)
                #pragma unroll
                for (int mt = 0; mt < 4; ++mt)
                    qf[kk][mt] = *(const bf16x8*)(Qf +
                        ((size_t)(b * L_ + m0 + mt * 16 + r16)) * 64 + kk * 32 + quad * 8);
            if (tid < 64) gS[tid] = scal[((size_t)(b * L_ + m0 + tid)) * 128 + 112];

            bf16x8 kf0, kf1;
            {
                const size_t kb = ((size_t)(b * L_ + tj0 * 64 + w * 16 + r16)) * 64 + quad * 8;
                kf0 = *(const bf16x8*)(Kf + kb);
                kf1 = *(const bf16x8*)(Kf + kb + 32);
            }

            for (int tj = tj0; tj < tj1; ++tj) {
                const size_t vb0 = (size_t)(n0 + w * 16 + r16) * 2048 + b * L_ + tj * 64 + quad * 8;
                bf16x8 vh0 = *(const bf16x8*)(Vthi + vb0);
                bf16x8 vh1 = *(const bf16x8*)(Vthi + vb0 + 32);
                bf16x8 vl0 = *(const bf16x8*)(Vtlo + vb0);
                bf16x8 vl1 = *(const bf16x8*)(Vtlo + vb0 + 32);

                f32x4 a4[4];
                #pragma unroll
                for (int mt = 0; mt < 4; ++mt) a4[mt] = (f32x4){0.f, 0.f, 0.f, 0.f};
                #pragma unroll
                for (int mt = 0; mt < 4; ++mt) {
                    a4[mt] = __builtin_amdgcn_mfma_f32_16x16x32_bf16(qf[0][mt], kf0, a4[mt], 0, 0, 0);
                    a4[mt] = __builtin_amdgcn_mfma_f32_16x16x32_bf16(qf[1][mt], kf1, a4[mt], 0, 0, 0);
                }
                if (tj + 1 < tj1) {
                    const size_t kb = ((size_t)(b * L_ + (tj + 1) * 64 + w * 16 + r16)) * 64 + quad * 8;
                    kf0 = *(const bf16x8*)(Kf + kb);
                    kf1 = *(const bf16x8*)(Kf + kb + 32);
                }

                __syncthreads();   // prior AV reads (or prior phase) done; gS ready
                const int lp = tj * 64 + w * 16 + r16;
                #pragma unroll
                for (int mt = 0; mt < 4; ++mt) {
                    #pragma unroll
                    for (int i = 0; i < 4; ++i) {
                        const int lr = mt * 16 + quad * 4 + i;
                        const int dl = (m0 + lr) - lp;
                        float v = 0.f;
                        if (dl >= 0)
                            v = a4[mt][i] + (1.0f - gS[lr]) * sw * gtab[dl];
                        unsigned short hi = f2bf(v);
                        Ah[lr * 68 + w * 16 + r16] = hi;
                        Al[lr * 68 + w * 16 + r16] = f2bf(v - bf2f(hi));
                    }
                }
                __syncthreads();   // A ready

                #pragma unroll
                for (int mt = 0; mt < 4; ++mt) {
                    bf16x8 ah0 = *(const bf16x8*)&Ah[(mt * 16 + r16) * 68 + quad * 8];
                    bf16x8 al0 = *(const bf16x8*)&Al[(mt * 16 + r16) * 68 + quad * 8];
                    bf16x8 ah1 = *(const bf16x8*)&Ah[(mt * 16 + r16) * 68 + 32 + quad * 8];
                    bf16x8 al1 = *(const bf16x8*)&Al[(mt * 16 + r16) * 68 + 32 + quad * 8];
                    accV[mt] = __builtin_amdgcn_mfma_f32_16x16x32_bf16(ah0, vh0, accV[mt], 0, 0, 0);
                    accV[mt] = __builtin_amdgcn_mfma_f32_16x16x32_bf16(ah0, vl0, accV[mt], 0, 0, 0);
                    accV[mt] = __builtin_amdgcn_mfma_f32_16x16x32_bf16(al0, vh0, accV[mt], 0, 0, 0);
                    accV[mt] = __builtin_amdgcn_mfma_f32_16x16x32_bf16(ah1, vh1, accV[mt], 0, 0, 0);
                    accV[mt] = __builtin_amdgcn_mfma_f32_16x16x32_bf16(ah1, vl1, accV[mt], 0, 0, 0);
                    accV[mt] = __builtin_amdgcn_mfma_f32_16x16x32_bf16(al1, vh1, accV[mt], 0, 0, 0);
                }
            }
        }

        const int n = n0 + w * 16 + r16;
        #pragma unroll
        for (int mt = 0; mt < 4; ++mt)
            #pragma unroll
            for (int i = 0; i < 4; ++i)
                prt[((size_t)(b * L_ + m0 + mt * 16 + quad * 4 + i)) * 512 + n] = accV[mt][i];
        __syncthreads();   // phase boundary: all waves done with Ah/Al/gS before next phase
    }
}

// ---------------- combine parts -> LN row sums ----------------
__global__ __launch_bounds__(256) void k_rs(
    const float* __restrict__ parts, float* __restrict__ rowsum)
{
    const int wv = threadIdx.x >> 6, lane = threadIdx.x & 63;
    #pragma unroll
    for (int rep = 0; rep < 2; ++rep) {
        const int row = blockIdx.x * 8 + wv * 2 + rep;
        const float* p0 = parts + (size_t)row * 512 + lane * 8;
        const float* p1 = p0 + (size_t)NROW * 512;
        float4 a0 = *(const float4*)p0,       a1 = *(const float4*)(p0 + 4);
        float4 b0 = *(const float4*)p1,       b1 = *(const float4*)(p1 + 4);
        float s = 0.f, s2 = 0.f;
        #pragma unroll
        for (int j = 0; j < 4; ++j) {
            float y0 = ((const float*)&a0)[j] + ((const float*)&b0)[j];
            float y1 = ((const float*)&a1)[j] + ((const float*)&b1)[j];
            s += y0 + y1; s2 += y0 * y0 + y1 * y1;
        }
        #pragma unroll
        for (int off = 32; off > 0; off >>= 1) {
            s  += __shfl_down(s, off, 64);
            s2 += __shfl_down(s2, off, 64);
        }
        if (lane == 0) { rowsum[row] = s; rowsum[2048 + row] = s2; }
    }
}

// ---------------- out GEMM + inline LayerNorm (verified R6) ----------------
__global__ __launch_bounds__(256) void k_gemm_out2(
    const float* __restrict__ parts, const float* __restrict__ rowsum,
    const unsigned short* __restrict__ OWt,
    const float* __restrict__ lng, const float* __restrict__ lnb,
    const float* __restrict__ bias, const float* __restrict__ resid,
    float* __restrict__ out)
{
    __shared__ unsigned short As[64 * 32];
    __shared__ unsigned short Bs[64 * 32];
    __shared__ float muS[64], rsS[64], nfiS[64];
    __shared__ float lgS[512], lbS[512];
    const int tid = threadIdx.x;
    const int w = tid >> 6;
    const int lane = tid & 63;
    const int m0 = blockIdx.y * 64;
    const int n0 = blockIdx.x * 64;
    const int srow = tid >> 2;
    const int scol = (tid & 3) * 8;
    const int quad = lane >> 4, r16 = lane & 15;

    if (tid < 64) {
        const int m = m0 + tid;
        const int l = m & (L_ - 1);
        float nf = sqrtf(4.0f * (float)(l + 1));
        float rs = rowsum[m], rq = rowsum[2048 + m];
        float mu = rs / (nf * 512.0f);
        float ey2 = rq / (nf * nf * 512.0f);
        float var = ey2 - mu * mu;
        muS[tid] = mu;
        rsS[tid] = rsqrtf(var + 1e-5f);
        nfiS[tid] = 1.0f / nf;
    }
    lgS[tid] = lng[tid];       lgS[256 + tid] = lng[256 + tid];
    lbS[tid] = lnb[tid];       lbS[256 + tid] = lnb[256 + tid];
    __syncthreads();

    f32x4 acc[4];
    #pragma unroll
    for (int mt = 0; mt < 4; ++mt) acc[mt] = (f32x4){0.f, 0.f, 0.f, 0.f};

    const float* ap0 = parts + (size_t)(m0 + srow) * 512 + scol;
    const float* ap1 = ap0 + (size_t)NROW * 512;
    const unsigned short* bp = OWt + (size_t)(n0 + srow) * 512 + scol;

    for (int k0 = 0; k0 < 512; k0 += 32) {
        float4 f0 = *(const float4*)(ap0 + k0);
        float4 f1 = *(const float4*)(ap0 + k0 + 4);
        float4 g0 = *(const float4*)(ap1 + k0);
        float4 g1 = *(const float4*)(ap1 + k0 + 4);
        int4 bv = *(const int4*)(bp + k0);
        const float mu = muS[srow], rstd = rsS[srow], nfi = nfiS[srow];
        float yv[8];
        yv[0] = f0.x + g0.x; yv[1] = f0.y + g0.y; yv[2] = f0.z + g0.z; yv[3] = f0.w + g0.w;
        yv[4] = f1.x + g1.x; yv[5] = f1.y + g1.y; yv[6] = f1.z + g1.z; yv[7] = f1.w + g1.w;
        unsigned short avs[8];
        #pragma unroll
        for (int j = 0; j < 8; ++j) {
            float yn = (yv[j] * nfi - mu) * rstd * lgS[k0 + scol + j] + lbS[k0 + scol + j];
            avs[j] = f2bf(yn);
        }
        __syncthreads();
        *(int4*)&As[srow * 32 + scol] = *(int4*)avs;
        *(int4*)&Bs[srow * 32 + scol] = bv;
        __syncthreads();
        bf16x8 bfr = *(const bf16x8*)&Bs[(w * 16 + r16) * 32 + quad * 8];
        #pragma unroll
        for (int mt = 0; mt < 4; ++mt) {
            bf16x8 af = *(const bf16x8*)&As[(mt * 16 + r16) * 32 + quad * 8];
            acc[mt] = __builtin_amdgcn_mfma_f32_16x16x32_bf16(af, bfr, acc[mt], 0, 0, 0);
        }
    }
    const int n = n0 + w * 16 + r16;
    const float bn = bias[n];
    #pragma unroll
    for (int mt = 0; mt < 4; ++mt) {
        #pragma unroll
        for (int i = 0; i < 4; ++i) {
            const int m = m0 + mt * 16 + quad * 4 + i;
            out[(size_t)m * 512 + n] = acc[mt][i] + bn + resid[(size_t)m * 512 + n];
        }
    }
}

extern "C" void kernel_launch(void* const* d_in, const int* in_sizes, int n_in,
                              void* d_out, int out_size, void* d_ws, size_t ws_size,
                              hipStream_t stream)
{
    const float* x      = (const float*)d_in[0];
    const float* keyw   = (const float*)d_in[1];
    const float* qryw   = (const float*)d_in[2];
    const float* vw     = (const float*)d_in[4];
    const float* vb     = (const float*)d_in[5];
    const float* lng    = (const float*)d_in[6];
    const float* lnb    = (const float*)d_in[7];
    const float* outw   = (const float*)d_in[8];
    const float* outb   = (const float*)d_in[9];
    const float* setw   = (const float*)d_in[10];
    const float* pf     = (const float*)d_in[11];
    const float* posw   = (const float*)d_in[12];
    const float* g1w    = (const float*)d_in[13];
    const float* g1b    = (const float*)d_in[14];
    const float* g2w    = (const float*)d_in[15];
    const float* g2b    = (const float*)d_in[16];
    const float* sscale = (const float*)d_in[19];
    const float* sbias  = (const float*)d_in[20];
    const float* rscale = (const float*)d_in[21];
    const float* rthr   = (const float*)d_in[22];

    char* wsb = (char*)d_ws;
    float*          R      = (float*)(wsb + 0);                  // 2.25 MiB
    float*          scal   = (float*)(wsb + 2359296);            // 1 MiB
    float*          parts  = (float*)(wsb + 3407872);            // 8 MiB (2 slots)
    unsigned short* W      = (unsigned short*)(wsb + 11796480);  // 1.375 MiB
    unsigned short* Vthi   = (unsigned short*)(wsb + 13238272);  // 2 MiB
    unsigned short* Vtlo   = (unsigned short*)(wsb + 15335424);  // 2 MiB
    unsigned short* Qf     = (unsigned short*)(wsb + 17432576);  // 256 KiB
    unsigned short* Kf     = (unsigned short*)(wsb + 17694720);  // 256 KiB
    float*          gtab   = (float*)(wsb + 17956864);           // 4 KiB
    float*          rowsum = (float*)(wsb + 17960960);           // 16 KiB
    float*          jkT    = (float*)(wsb + 17977344);           // 64 KiB
    float*          kmT    = (float*)(wsb + 18042880);           // 64 KiB

    float* out = (float*)d_out;

    k_prep_w<<<176, 256, 0, stream>>>(keyw, qryw, g1w, vw, outw, W);
    k_gemm1v<<<dim3(14, 32), 256, 0, stream>>>(x, W, g1b, vb, R, Vthi, Vtlo);
    k_phasor<<<NROW / 4, 256, 0, stream>>>(R, g2w, g2b, scal, jkT);
    k_scanw<<<17, 64, 0, stream>>>(jkT, pf, kmT, gtab);
    k_build<<<32, 64, 0, stream>>>(scal, kmT, rscale, rthr, sscale, sbias, setw, Qf, Kf);
    k_avS<<<256, 256, 0, stream>>>(Qf, Kf, scal, gtab, posw, Vthi, Vtlo, parts);
    k_rs<<<256, 256, 0, stream>>>(parts, rowsum);
    k_gemm_out2<<<dim3(8, 32), 256, 0, stream>>>(parts, rowsum, W + (size_t)896 * 512,
                                                 lng, lnb, outb, x, out);
}

// Round 8
// 180.380 us; speedup vs baseline: 1.2463x; 1.1362x over previous
//
#include <hip/hip_runtime.h>
#include <math.h>

#define B_ 2
#define L_ 1024
#define D_ 512
#define NROW 2048
#define RS 288                  // R stride: key16|query16|g1 256
#define PI_F 3.14159274f
#define TWO_PI_F 6.28318548f

typedef __attribute__((ext_vector_type(8))) short bf16x8;
typedef __attribute__((ext_vector_type(4))) float f32x4;

__device__ __forceinline__ unsigned short f2bf(float f) {
    unsigned u = __float_as_uint(f);
    unsigned r = (u + 0x7FFFu + ((u >> 16) & 1u)) >> 16;
    return (unsigned short)r;
}
__device__ __forceinline__ float bf2f(unsigned short h) {
    return __uint_as_float((unsigned)h << 16);
}
__device__ __forceinline__ unsigned pack2(float a, float b) {
    return (unsigned)f2bf(a) | ((unsigned)f2bf(b) << 16);
}

// ---------------- weight prep: tiled transpose + bf16 cast (verified R1) ----------------
__global__ __launch_bounds__(256) void k_prep_w(
    const float* __restrict__ keyw, const float* __restrict__ qryw,
    const float* __restrict__ g1w, const float* __restrict__ vw,
    const float* __restrict__ outw, unsigned short* __restrict__ W)
{
    const int nt = blockIdx.x % 22;
    const int kt = blockIdx.x / 22;
    const int n0 = nt * 64, k0 = kt * 64;
    __shared__ unsigned short tile[64 * 68];
    const int tn = threadIdx.x & 63;
    const int tk4 = threadIdx.x >> 6;
    const int n = n0 + tn;
    const float* src = nullptr; int stride = 0, col = 0;
    if (n < 16)        { src = keyw; stride = 16;  col = n; }
    else if (n < 32)   { src = qryw; stride = 16;  col = n - 16; }
    else if (n < 288)  { src = g1w;  stride = 256; col = n - 32; }
    else if (n < 800)  { src = vw;   stride = 512; col = n - 288; }
    else if (n < 896)  { src = nullptr; }
    else               { src = outw; stride = 512; col = n - 896; }
    #pragma unroll
    for (int r = 0; r < 16; ++r) {
        int k = k0 + tk4 * 16 + r;
        float v = src ? src[(size_t)k * stride + col] : 0.f;
        tile[(tk4 * 16 + r) * 68 + tn] = f2bf(v);
    }
    __syncthreads();
    #pragma unroll
    for (int r = 0; r < 16; ++r) {
        int nn = n0 + tk4 * 16 + r;
        W[(size_t)nn * 512 + k0 + tn] = tile[tn * 68 + tk4 * 16 + r];
    }
}

// ---------------- GEMM1 (64x64 tiles, 448 blocks): R + Vt hi/lo (verified R7) ----------------
__global__ __launch_bounds__(256) void k_gemm1v(
    const float* __restrict__ x,
    const unsigned short* __restrict__ Bt,
    const float* __restrict__ g1b, const float* __restrict__ vb,
    float* __restrict__ R,
    unsigned short* __restrict__ Vthi, unsigned short* __restrict__ Vtlo)
{
    __shared__ unsigned short As[64 * 32];
    __shared__ unsigned short Bs[64 * 32];
    const int tid = threadIdx.x;
    const int w = tid >> 6;
    const int lane = tid & 63;
    const int m0 = blockIdx.y * 64;
    const int n0 = blockIdx.x * 64;
    const int srow = tid >> 2;
    const int scol = (tid & 3) * 8;
    const int quad = lane >> 4, r16 = lane & 15;

    f32x4 acc[4];
    #pragma unroll
    for (int mt = 0; mt < 4; ++mt) acc[mt] = (f32x4){0.f, 0.f, 0.f, 0.f};

    const float* ap = x + (size_t)(m0 + srow) * 512 + scol;
    const unsigned short* bp = Bt + (size_t)(n0 + srow) * 512 + scol;

    for (int k0 = 0; k0 < 512; k0 += 32) {
        float4 a0 = *(const float4*)(ap + k0);
        float4 a1 = *(const float4*)(ap + k0 + 4);
        int4 bv = *(const int4*)(bp + k0);
        int4 av;
        av.x = (int)f2bf(a0.x) | ((int)f2bf(a0.y) << 16);
        av.y = (int)f2bf(a0.z) | ((int)f2bf(a0.w) << 16);
        av.z = (int)f2bf(a1.x) | ((int)f2bf(a1.y) << 16);
        av.w = (int)f2bf(a1.z) | ((int)f2bf(a1.w) << 16);
        __syncthreads();
        *(int4*)&As[srow * 32 + scol] = av;
        *(int4*)&Bs[srow * 32 + scol] = bv;
        __syncthreads();
        bf16x8 bfr = *(const bf16x8*)&Bs[(w * 16 + r16) * 32 + quad * 8];
        #pragma unroll
        for (int mt = 0; mt < 4; ++mt) {
            bf16x8 af = *(const bf16x8*)&As[(mt * 16 + r16) * 32 + quad * 8];
            acc[mt] = __builtin_amdgcn_mfma_f32_16x16x32_bf16(af, bfr, acc[mt], 0, 0, 0);
        }
    }

    const int n = n0 + w * 16 + r16;
    if (n < 288) {
        const float bias = (n >= 32) ? g1b[n - 32] : 0.f;
        #pragma unroll
        for (int mt = 0; mt < 4; ++mt)
            #pragma unroll
            for (int i = 0; i < 4; ++i) {
                const int m = m0 + mt * 16 + quad * 4 + i;
                R[(size_t)m * RS + n] = acc[mt][i] + bias;
            }
    } else if (n < 800) {
        const int d = n - 288;
        const float bias = vb[d];
        #pragma unroll
        for (int mt = 0; mt < 4; ++mt) {
            ushort4 h4, l4;
            #pragma unroll
            for (int i = 0; i < 4; ++i) {
                float v = acc[mt][i] + bias;
                unsigned short hi = f2bf(v);
                ((unsigned short*)&h4)[i] = hi;
                ((unsigned short*)&l4)[i] = f2bf(v - bf2f(hi));
            }
            const size_t vo = (size_t)d * 2048 + m0 + mt * 16 + quad * 4;
            *(ushort4*)&Vthi[vo] = h4;
            *(ushort4*)&Vtlo[vo] = l4;
        }
    }
}

// ---------------- phasors, jk/jq, gate + compact jkT (verified R7) ----------------
__global__ __launch_bounds__(256) void k_phasor(
    const float* __restrict__ R,
    const float* __restrict__ g2w, const float* __restrict__ g2b,
    float* __restrict__ scal, float* __restrict__ jkT)
{
    const int row = blockIdx.x * 4 + (threadIdx.x >> 6);
    const int lane = threadIdx.x & 63;
    const int b = row >> 10, l = row & (L_ - 1);
    float* sc = scal + (size_t)row * 128;
    const float* r = R + (size_t)row * RS;

    float part = 0.f;
    #pragma unroll
    for (int j = 0; j < 4; ++j) {
        float v = r[32 + lane * 4 + j];
        float h = 0.5f * v * (1.0f + erff(v * 0.70710678f));
        part += h * g2w[lane * 4 + j];
    }
    #pragma unroll
    for (int off = 32; off > 0; off >>= 1) part += __shfl_down(part, off, 64);
    if (lane == 0) sc[112] = 1.0f / (1.0f + expf(-(part + g2b[0])));

    float pr = 1.f, pim = 0.f;
    if (lane < 32) {
        float a = tanhf(r[lane]) * PI_F;
        float sv, cv;
        sincosf(a, &sv, &cv);
        int t = lane & 15;
        if (lane < 16) { sc[t] = cv; sc[16 + t] = sv; }
        else           { sc[32 + t] = cv; sc[48 + t] = sv; }
        pr = cv; pim = sv;
    }
    #pragma unroll
    for (int m = 4; m <= 8; m <<= 1) {
        float orr = __shfl_xor(pr, m, 64);
        float oii = __shfl_xor(pim, m, 64);
        float nr = pr * orr - pim * oii;
        float ni = pr * oii + pim * orr;
        pr = nr; pim = ni;
    }
    if (lane < 4) {
        sc[64 + lane] = pr; sc[68 + lane] = pim;
        jkT[(size_t)(b * 8 + lane) * L_ + l]     = pr;
        jkT[(size_t)(b * 8 + 4 + lane) * L_ + l] = pim;
    } else if (lane >= 16 && lane < 20) {
        sc[72 + lane - 16] = pr; sc[76 + lane - 16] = pim;
    }
}

// ---------------- wide block scan: 16 channels, one 256-thr block each (+gtab block) ----------------
__global__ __launch_bounds__(256) void k_scan16(
    const float* __restrict__ jkT, const float* __restrict__ pf,
    float* __restrict__ kmT, float* __restrict__ gtab)
{
    const int bx = blockIdx.x;
    const int tid = threadIdx.x;
    if (bx == 16) {
        #pragma unroll
        for (int j = 0; j < 4; ++j) {
            const int l = tid * 4 + j;
            float g = 0.f;
            #pragma unroll
            for (int p = 0; p < 16; ++p)
                g += cosf(TWO_PI_F * (float)l * pf[p]);
            gtab[l] = g;
        }
        return;
    }
    const int lane = tid & 63, wv = tid >> 6;
    __shared__ float wtot[4];
    float4 v = ((const float4*)(jkT + (size_t)bx * L_))[tid];
    float s = v.x + v.y + v.z + v.w;
    float incl = s;
    #pragma unroll
    for (int off = 1; off < 64; off <<= 1) {
        float o = __shfl_up(incl, off, 64);
        if (lane >= off) incl += o;
    }
    if (lane == 63) wtot[wv] = incl;
    __syncthreads();
    float pre = incl - s;
    for (int w2 = 0; w2 < wv; ++w2) pre += wtot[w2];
    float4 out;
    out.x = pre;
    out.y = pre + v.x;
    out.z = out.y + v.y;
    out.w = out.z + v.z;
    ((float4*)(kmT + (size_t)bx * L_))[tid] = out;
}

// ---------------- build: wgv inline + Qf/Kf rows (R3 row-parallel form) ----------------
__global__ __launch_bounds__(256) void k_build(
    const float* __restrict__ scal, const float* __restrict__ kmT,
    const float* __restrict__ res_scale, const float* __restrict__ res_thr,
    const float* __restrict__ sur_scale, const float* __restrict__ sur_bias,
    const float* __restrict__ setw,
    unsigned short* __restrict__ Qf, unsigned short* __restrict__ Kf)
{
    const int rowi = blockIdx.x * 8 + (threadIdx.x >> 5);
    const int sub = threadIdx.x & 31;
    const int b = rowi >> 10, l = rowi & (L_ - 1);
    const float* sc = scal + (size_t)rowi * 128;

    // wgv (redundant per thread; same-row loads broadcast within wave)
    float mag = 0.f;
    #pragma unroll
    for (int pp = 0; pp < 4; ++pp) {
        float kmr = kmT[(size_t)(b * 8 + pp) * L_ + l];
        float kmi = kmT[(size_t)(b * 8 + 4 + pp) * L_ + l];
        float jqr = sc[72 + pp], jqi = sc[76 + pp];
        float re = kmr * jqr + kmi * jqi;
        float im = kmi * jqr - kmr * jqi;
        mag += sqrtf(re * re + im * im);
    }
    mag *= 0.25f;
    float posn = fmaxf((float)l, 1.0f);
    float nres = mag / sqrtf(posn);
    float scl = fminf(fmaxf(res_scale[0], 1.0f), 20.0f);
    float thr = fminf(fmaxf(res_thr[0], 0.1f), 0.9f);
    float sur = 0.5f * (1.0f - tanhf(scl * (nres - thr)));
    float wgv = 1.0f / (1.0f + expf(-(sur_scale[0] * (sur - 0.5f) + sur_bias[0])));

    const float gate = sc[112];
    float s0 = setw[0], s1 = setw[1], s2 = setw[2], s3 = setw[3];
    float mx = fmaxf(fmaxf(s0, s1), fmaxf(s2, s3));
    float e0 = expf(s0 - mx), e1 = expf(s1 - mx), e2 = expf(s2 - mx), e3 = expf(s3 - mx);
    float esum = e0 + e1 + e2 + e3;
    const float qs = 0.2f * gate;

    unsigned* qp = (unsigned*)(Qf + (size_t)rowi * 64);
    unsigned* kp = (unsigned*)(Kf + (size_t)rowi * 64);
    if (sub < 16) {
        float wgrp = ((sub >> 2) == 0 ? e0 : (sub >> 2) == 1 ? e1 : (sub >> 2) == 2 ? e2 : e3) / esum;
        qp[sub] = pack2(qs * wgrp * sc[32 + sub], qs * wgrp * sc[48 + sub]);
        kp[sub] = pack2(wgv * sc[sub], wgv * sc[16 + sub]);
    } else if (sub < 20) {
        int p = sub - 16;
        qp[16 + p] = pack2(qs * sc[72 + p], qs * sc[76 + p]);
        kp[16 + p] = pack2(wgv * sc[64 + p], wgv * sc[68 + p]);
    } else {
        qp[sub] = 0u; kp[sub] = 0u;
    }
}

// ---------------- build A (tril 64x64 tiles): A = Qf@Kf^T + toeplitz, bf16 hi/lo (verified R3) ----------------
__global__ __launch_bounds__(256) void k_buildA(
    const unsigned short* __restrict__ Qf, const unsigned short* __restrict__ Kf,
    const float* __restrict__ scal, const float* __restrict__ gtab,
    const float* __restrict__ posw,
    unsigned short* __restrict__ Ahi, unsigned short* __restrict__ Alo)
{
    const int bx = blockIdx.x;
    const int b = bx / 136;
    const int r = bx % 136;
    int ti = 0;
    while ((ti + 1) * (ti + 2) / 2 <= r) ++ti;
    const int tj = r - ti * (ti + 1) / 2;

    __shared__ unsigned short Qs[64 * 72];
    __shared__ unsigned short Ks[64 * 72];
    const int tid = threadIdx.x;
    const int srow = tid >> 2;
    const int sc16 = (tid & 3) * 16;
    {
        const unsigned short* qsrc = Qf + ((size_t)(b * L_ + ti * 64 + srow)) * 64 + sc16;
        const unsigned short* ksrc = Kf + ((size_t)(b * L_ + tj * 64 + srow)) * 64 + sc16;
        *(int4*)&Qs[srow * 72 + sc16]     = *(const int4*)(qsrc);
        *(int4*)&Qs[srow * 72 + sc16 + 8] = *(const int4*)(qsrc + 8);
        *(int4*)&Ks[srow * 72 + sc16]     = *(const int4*)(ksrc);
        *(int4*)&Ks[srow * 72 + sc16 + 8] = *(const int4*)(ksrc + 8);
    }
    __syncthreads();

    const int w = tid >> 6;
    const int lane = tid & 63;
    const int quad = lane >> 4, r16 = lane & 15;
    f32x4 acc[4];
    #pragma unroll
    for (int mt = 0; mt < 4; ++mt) acc[mt] = (f32x4){0.f, 0.f, 0.f, 0.f};
    #pragma unroll
    for (int kk = 0; kk < 2; ++kk) {
        bf16x8 bfr = *(const bf16x8*)&Ks[(w * 16 + r16) * 72 + kk * 32 + quad * 8];
        #pragma unroll
        for (int mt = 0; mt < 4; ++mt) {
            bf16x8 af = *(const bf16x8*)&Qs[(mt * 16 + r16) * 72 + kk * 32 + quad * 8];
            acc[mt] = __builtin_amdgcn_mfma_f32_16x16x32_bf16(af, bfr, acc[mt], 0, 0, 0);
        }
    }
    const float sw = 1.0f / (1.0f + expf(-posw[0]));
    const int lp = tj * 64 + w * 16 + r16;
    #pragma unroll
    for (int mt = 0; mt < 4; ++mt) {
        #pragma unroll
        for (int i = 0; i < 4; ++i) {
            const int l = ti * 64 + mt * 16 + quad * 4 + i;
            const int dl = l - lp;
            float v = 0.f;
            if (dl >= 0) {
                float gate = scal[((size_t)(b * L_ + l)) * 128 + 112];
                v = acc[mt][i] + (1.0f - gate) * sw * gtab[dl];
            }
            unsigned short hi = f2bf(v);
            unsigned short lo = f2bf(v - bf2f(hi));
            const size_t off = ((size_t)(b * L_ + l)) * 1024 + lp;
            Ahi[off] = hi;
            Alo[off] = lo;
        }
    }
}

// ---------------- AV GEMM, h-split + b-flip balance (R3 av loop + R6 bounds) ----------------
__global__ __launch_bounds__(256) void k_avH(
    const unsigned short* __restrict__ Ahi, const unsigned short* __restrict__ Alo,
    const unsigned short* __restrict__ Vthi, const unsigned short* __restrict__ Vtlo,
    float* __restrict__ parts)
{
    const int bx = blockIdx.x;          // b(1)|ti0(4)|nj(3)|h(1) = 512
    const int h  = bx & 1;
    const int nj = (bx >> 1) & 7;
    const int ti0 = (bx >> 4) & 15;
    const int b  = bx >> 8;
    const int ti = b ? (15 - ti0) : ti0;   // flip for per-CU balance
    const int m0 = ti * 64, n0 = nj * 64;
    const int nh = (ti + 2) >> 1;
    const int kbeg = (h ? nh : 0) * 64;
    const int kend = (h ? (ti + 1) : nh) * 64;
    float* prt = parts + (size_t)h * NROW * 512;

    __shared__ unsigned short Ash[64 * 32];
    __shared__ unsigned short Asl[64 * 32];
    __shared__ unsigned short Bsh[64 * 32];
    __shared__ unsigned short Bsl[64 * 32];
    const int tid = threadIdx.x;
    const int w = tid >> 6;
    const int lane = tid & 63;
    const int srow = tid >> 2;
    const int scol = (tid & 3) * 8;
    const int quad = lane >> 4, r16 = lane & 15;

    f32x4 acc[4];
    #pragma unroll
    for (int mt = 0; mt < 4; ++mt) acc[mt] = (f32x4){0.f, 0.f, 0.f, 0.f};

    const unsigned short* aph = Ahi + ((size_t)(b * L_ + m0 + srow)) * 1024 + scol;
    const unsigned short* apl = Alo + ((size_t)(b * L_ + m0 + srow)) * 1024 + scol;
    const unsigned short* bph = Vthi + (size_t)(n0 + srow) * 2048 + b * L_ + scol;
    const unsigned short* bpl = Vtlo + (size_t)(n0 + srow) * 2048 + b * L_ + scol;

    for (int k0 = kbeg; k0 < kend; k0 += 32) {
        int4 ah = *(const int4*)(aph + k0);
        int4 al = *(const int4*)(apl + k0);
        int4 bh = *(const int4*)(bph + k0);
        int4 bl = *(const int4*)(bpl + k0);
        __syncthreads();
        *(int4*)&Ash[srow * 32 + scol] = ah;
        *(int4*)&Asl[srow * 32 + scol] = al;
        *(int4*)&Bsh[srow * 32 + scol] = bh;
        *(int4*)&Bsl[srow * 32 + scol] = bl;
        __syncthreads();
        bf16x8 bh8 = *(const bf16x8*)&Bsh[(w * 16 + r16) * 32 + quad * 8];
        bf16x8 bl8 = *(const bf16x8*)&Bsl[(w * 16 + r16) * 32 + quad * 8];
        #pragma unroll
        for (int mt = 0; mt < 4; ++mt) {
            bf16x8 ah8 = *(const bf16x8*)&Ash[(mt * 16 + r16) * 32 + quad * 8];
            bf16x8 al8 = *(const bf16x8*)&Asl[(mt * 16 + r16) * 32 + quad * 8];
            acc[mt] = __builtin_amdgcn_mfma_f32_16x16x32_bf16(ah8, bh8, acc[mt], 0, 0, 0);
            acc[mt] = __builtin_amdgcn_mfma_f32_16x16x32_bf16(ah8, bl8, acc[mt], 0, 0, 0);
            acc[mt] = __builtin_amdgcn_mfma_f32_16x16x32_bf16(al8, bh8, acc[mt], 0, 0, 0);
        }
    }
    const int n = n0 + w * 16 + r16;
    #pragma unroll
    for (int mt = 0; mt < 4; ++mt)
        #pragma unroll
        for (int i = 0; i < 4; ++i)
            prt[((size_t)(b * L_ + m0 + mt * 16 + quad * 4 + i)) * 512 + n] = acc[mt][i];
}

// ---------------- combine parts -> LN row sums (verified R6/R7) ----------------
__global__ __launch_bounds__(256) void k_rs(
    const float* __restrict__ parts, float* __restrict__ rowsum)
{
    const int wv = threadIdx.x >> 6, lane = threadIdx.x & 63;
    #pragma unroll
    for (int rep = 0; rep < 2; ++rep) {
        const int row = blockIdx.x * 8 + wv * 2 + rep;
        const float* p0 = parts + (size_t)row * 512 + lane * 8;
        const float* p1 = p0 + (size_t)NROW * 512;
        float4 a0 = *(const float4*)p0,       a1 = *(const float4*)(p0 + 4);
        float4 b0 = *(const float4*)p1,       b1 = *(const float4*)(p1 + 4);
        float s = 0.f, s2 = 0.f;
        #pragma unroll
        for (int j = 0; j < 4; ++j) {
            float y0 = ((const float*)&a0)[j] + ((const float*)&b0)[j];
            float y1 = ((const float*)&a1)[j] + ((const float*)&b1)[j];
            s += y0 + y1; s2 += y0 * y0 + y1 * y1;
        }
        #pragma unroll
        for (int off = 32; off > 0; off >>= 1) {
            s  += __shfl_down(s, off, 64);
            s2 += __shfl_down(s2, off, 64);
        }
        if (lane == 0) { rowsum[row] = s; rowsum[2048 + row] = s2; }
    }
}

// ---------------- out GEMM + inline LayerNorm (verified R6/R7) ----------------
__global__ __launch_bounds__(256) void k_gemm_out2(
    const float* __restrict__ parts, const float* __restrict__ rowsum,
    const unsigned short* __restrict__ OWt,
    const float* __restrict__ lng, const float* __restrict__ lnb,
    const float* __restrict__ bias, const float* __restrict__ resid,
    float* __restrict__ out)
{
    __shared__ unsigned short As[64 * 32];
    __shared__ unsigned short Bs[64 * 32];
    __shared__ float muS[64], rsS[64], nfiS[64];
    __shared__ float lgS[512], lbS[512];
    const int tid = threadIdx.x;
    const int w = tid >> 6;
    const int lane = tid & 63;
    const int m0 = blockIdx.y * 64;
    const int n0 = blockIdx.x * 64;
    const int srow = tid >> 2;
    const int scol = (tid & 3) * 8;
    const int quad = lane >> 4, r16 = lane & 15;

    if (tid < 64) {
        const int m = m0 + tid;
        const int l = m & (L_ - 1);
        float nf = sqrtf(4.0f * (float)(l + 1));
        float rs = rowsum[m], rq = rowsum[2048 + m];
        float mu = rs / (nf * 512.0f);
        float ey2 = rq / (nf * nf * 512.0f);
        float var = ey2 - mu * mu;
        muS[tid] = mu;
        rsS[tid] = rsqrtf(var + 1e-5f);
        nfiS[tid] = 1.0f / nf;
    }
    lgS[tid] = lng[tid];       lgS[256 + tid] = lng[256 + tid];
    lbS[tid] = lnb[tid];       lbS[256 + tid] = lnb[256 + tid];
    __syncthreads();

    f32x4 acc[4];
    #pragma unroll
    for (int mt = 0; mt < 4; ++mt) acc[mt] = (f32x4){0.f, 0.f, 0.f, 0.f};

    const float* ap0 = parts + (size_t)(m0 + srow) * 512 + scol;
    const float* ap1 = ap0 + (size_t)NROW * 512;
    const unsigned short* bp = OWt + (size_t)(n0 + srow) * 512 + scol;

    for (int k0 = 0; k0 < 512; k0 += 32) {
        float4 f0 = *(const float4*)(ap0 + k0);
        float4 f1 = *(const float4*)(ap0 + k0 + 4);
        float4 g0 = *(const float4*)(ap1 + k0);
        float4 g1 = *(const float4*)(ap1 + k0 + 4);
        int4 bv = *(const int4*)(bp + k0);
        const float mu = muS[srow], rstd = rsS[srow], nfi = nfiS[srow];
        float yv[8];
        yv[0] = f0.x + g0.x; yv[1] = f0.y + g0.y; yv[2] = f0.z + g0.z; yv[3] = f0.w + g0.w;
        yv[4] = f1.x + g1.x; yv[5] = f1.y + g1.y; yv[6] = f1.z + g1.z; yv[7] = f1.w + g1.w;
        unsigned short avs[8];
        #pragma unroll
        for (int j = 0; j < 8; ++j) {
            float yn = (yv[j] * nfi - mu) * rstd * lgS[k0 + scol + j] + lbS[k0 + scol + j];
            avs[j] = f2bf(yn);
        }
        __syncthreads();
        *(int4*)&As[srow * 32 + scol] = *(int4*)avs;
        *(int4*)&Bs[srow * 32 + scol] = bv;
        __syncthreads();
        bf16x8 bfr = *(const bf16x8*)&Bs[(w * 16 + r16) * 32 + quad * 8];
        #pragma unroll
        for (int mt = 0; mt < 4; ++mt) {
            bf16x8 af = *(const bf16x8*)&As[(mt * 16 + r16) * 32 + quad * 8];
            acc[mt] = __builtin_amdgcn_mfma_f32_16x16x32_bf16(af, bfr, acc[mt], 0, 0, 0);
        }
    }
    const int n = n0 + w * 16 + r16;
    const float bn = bias[n];
    #pragma unroll
    for (int mt = 0; mt < 4; ++mt) {
        #pragma unroll
        for (int i = 0; i < 4; ++i) {
            const int m = m0 + mt * 16 + quad * 4 + i;
            out[(size_t)m * 512 + n] = acc[mt][i] + bn + resid[(size_t)m * 512 + n];
        }
    }
}

extern "C" void kernel_launch(void* const* d_in, const int* in_sizes, int n_in,
                              void* d_out, int out_size, void* d_ws, size_t ws_size,
                              hipStream_t stream)
{
    const float* x      = (const float*)d_in[0];
    const float* keyw   = (const float*)d_in[1];
    const float* qryw   = (const float*)d_in[2];
    const float* vw     = (const float*)d_in[4];
    const float* vb     = (const float*)d_in[5];
    const float* lng    = (const float*)d_in[6];
    const float* lnb    = (const float*)d_in[7];
    const float* outw   = (const float*)d_in[8];
    const float* outb   = (const float*)d_in[9];
    const float* setw   = (const float*)d_in[10];
    const float* pf     = (const float*)d_in[11];
    const float* posw   = (const float*)d_in[12];
    const float* g1w    = (const float*)d_in[13];
    const float* g1b    = (const float*)d_in[14];
    const float* g2w    = (const float*)d_in[15];
    const float* g2b    = (const float*)d_in[16];
    const float* sscale = (const float*)d_in[19];
    const float* sbias  = (const float*)d_in[20];
    const float* rscale = (const float*)d_in[21];
    const float* rthr   = (const float*)d_in[22];

    char* wsb = (char*)d_ws;
    float*          R      = (float*)(wsb + 0);                  // 2.25 MiB
    float*          scal   = (float*)(wsb + 2359296);            // 1 MiB
    float*          parts  = (float*)(wsb + 3407872);            // 8 MiB (2 slots)
    unsigned short* W      = (unsigned short*)(wsb + 11796480);  // 1.375 MiB
    unsigned short* Vthi   = (unsigned short*)(wsb + 13238272);  // 2 MiB
    unsigned short* Vtlo   = (unsigned short*)(wsb + 15335424);  // 2 MiB
    unsigned short* Qf     = (unsigned short*)(wsb + 17432576);  // 256 KiB
    unsigned short* Kf     = (unsigned short*)(wsb + 17694720);  // 256 KiB
    float*          gtab   = (float*)(wsb + 17956864);           // 4 KiB
    float*          rowsum = (float*)(wsb + 17960960);           // 16 KiB
    float*          jkT    = (float*)(wsb + 17977344);           // 64 KiB
    float*          kmT    = (float*)(wsb + 18042880);           // 64 KiB
    unsigned short* Ahi    = (unsigned short*)(wsb + 18108416);  // 4 MiB
    unsigned short* Alo    = (unsigned short*)(wsb + 22302720);  // 4 MiB

    float* out = (float*)d_out;

    k_prep_w<<<176, 256, 0, stream>>>(keyw, qryw, g1w, vw, outw, W);
    k_gemm1v<<<dim3(14, 32), 256, 0, stream>>>(x, W, g1b, vb, R, Vthi, Vtlo);
    k_phasor<<<NROW / 4, 256, 0, stream>>>(R, g2w, g2b, scal, jkT);
    k_scan16<<<17, 256, 0, stream>>>(jkT, pf, kmT, gtab);
    k_build<<<256, 256, 0, stream>>>(scal, kmT, rscale, rthr, sscale, sbias, setw, Qf, Kf);
    k_buildA<<<2 * 136, 256, 0, stream>>>(Qf, Kf, scal, gtab, posw, Ahi, Alo);
    k_avH<<<512, 256, 0, stream>>>(Ahi, Alo, Vthi, Vtlo, parts);
    k_rs<<<256, 256, 0, stream>>>(parts, rowsum);
    k_gemm_out2<<<dim3(8, 32), 256, 0, stream>>>(parts, rowsum, W + (size_t)896 * 512,
                                                 lng, lnb, outb, x, out);
}

// Round 9
// 164.806 us; speedup vs baseline: 1.3641x; 1.0945x over previous
//
#include <hip/hip_runtime.h>
#include <math.h>

#define B_ 2
#define L_ 1024
#define D_ 512
#define NROW 2048
#define RS 288                  // R stride: key16|query16|g1 256
#define PI_F 3.14159274f
#define TWO_PI_F 6.28318548f

typedef __attribute__((ext_vector_type(8))) short bf16x8;
typedef __attribute__((ext_vector_type(4))) float f32x4;

__device__ __forceinline__ unsigned short f2bf(float f) {
    unsigned u = __float_as_uint(f);
    unsigned r = (u + 0x7FFFu + ((u >> 16) & 1u)) >> 16;
    return (unsigned short)r;
}
__device__ __forceinline__ float bf2f(unsigned short h) {
    return __uint_as_float((unsigned)h << 16);
}
__device__ __forceinline__ unsigned pack2(float a, float b) {
    return (unsigned)f2bf(a) | ((unsigned)f2bf(b) << 16);
}

// ---------------- weight prep + x cast + gtab ----------------
// blocks 0..175: W transpose (verified R1); 176..303: x->bf16; 304: gtab
__global__ __launch_bounds__(256) void k_prep_w(
    const float* __restrict__ keyw, const float* __restrict__ qryw,
    const float* __restrict__ g1w, const float* __restrict__ vw,
    const float* __restrict__ outw, const float* __restrict__ x,
    const float* __restrict__ pf,
    unsigned short* __restrict__ W, unsigned short* __restrict__ xb,
    float* __restrict__ gtab)
{
    const int bx = blockIdx.x;
    const int tid = threadIdx.x;
    if (bx >= 304) {                       // gtab
        #pragma unroll
        for (int j = 0; j < 4; ++j) {
            const int l = tid * 4 + j;
            float g = 0.f;
            #pragma unroll
            for (int p = 0; p < 16; ++p)
                g += cosf(TWO_PI_F * (float)l * pf[p]);
            gtab[l] = g;
        }
        return;
    }
    if (bx >= 176) {                       // x cast: 128 blocks x 2048 float4
        const int chunk = (bx - 176) * 2048;       // float4 units
        const float4* x4 = (const float4*)x;
        ushort4* xb4 = (ushort4*)xb;
        #pragma unroll
        for (int j = 0; j < 8; ++j) {
            float4 v = x4[chunk + j * 256 + tid];
            ushort4 o;
            o.x = f2bf(v.x); o.y = f2bf(v.y); o.z = f2bf(v.z); o.w = f2bf(v.w);
            xb4[chunk + j * 256 + tid] = o;
        }
        return;
    }
    const int nt = bx % 22;
    const int kt = bx / 22;
    const int n0 = nt * 64, k0 = kt * 64;
    __shared__ unsigned short tile[64 * 68];
    const int tn = tid & 63;
    const int tk4 = tid >> 6;
    const int n = n0 + tn;
    const float* src = nullptr; int stride = 0, col = 0;
    if (n < 16)        { src = keyw; stride = 16;  col = n; }
    else if (n < 32)   { src = qryw; stride = 16;  col = n - 16; }
    else if (n < 288)  { src = g1w;  stride = 256; col = n - 32; }
    else if (n < 800)  { src = vw;   stride = 512; col = n - 288; }
    else if (n < 896)  { src = nullptr; }
    else               { src = outw; stride = 512; col = n - 896; }
    #pragma unroll
    for (int r = 0; r < 16; ++r) {
        int k = k0 + tk4 * 16 + r;
        float v = src ? src[(size_t)k * stride + col] : 0.f;
        tile[(tk4 * 16 + r) * 68 + tn] = f2bf(v);
    }
    __syncthreads();
    #pragma unroll
    for (int r = 0; r < 16; ++r) {
        int nn = n0 + tk4 * 16 + r;
        W[(size_t)nn * 512 + k0 + tn] = tile[tn * 68 + tk4 * 16 + r];
    }
}

// ---------------- GEMM1 (64x64 tiles, 448 blocks): A=xb bf16; R + Vt hi/lo ----------------
__global__ __launch_bounds__(256) void k_gemm1v(
    const unsigned short* __restrict__ xb,
    const unsigned short* __restrict__ Bt,
    const float* __restrict__ g1b, const float* __restrict__ vb,
    float* __restrict__ R,
    unsigned short* __restrict__ Vthi, unsigned short* __restrict__ Vtlo)
{
    __shared__ unsigned short As[64 * 32];
    __shared__ unsigned short Bs[64 * 32];
    const int tid = threadIdx.x;
    const int w = tid >> 6;
    const int lane = tid & 63;
    const int m0 = blockIdx.y * 64;
    const int n0 = blockIdx.x * 64;
    const int srow = tid >> 2;
    const int scol = (tid & 3) * 8;
    const int quad = lane >> 4, r16 = lane & 15;

    f32x4 acc[4];
    #pragma unroll
    for (int mt = 0; mt < 4; ++mt) acc[mt] = (f32x4){0.f, 0.f, 0.f, 0.f};

    const unsigned short* ap = xb + (size_t)(m0 + srow) * 512 + scol;
    const unsigned short* bp = Bt + (size_t)(n0 + srow) * 512 + scol;

    for (int k0 = 0; k0 < 512; k0 += 32) {
        int4 av = *(const int4*)(ap + k0);
        int4 bv = *(const int4*)(bp + k0);
        __syncthreads();
        *(int4*)&As[srow * 32 + scol] = av;
        *(int4*)&Bs[srow * 32 + scol] = bv;
        __syncthreads();
        bf16x8 bfr = *(const bf16x8*)&Bs[(w * 16 + r16) * 32 + quad * 8];
        #pragma unroll
        for (int mt = 0; mt < 4; ++mt) {
            bf16x8 af = *(const bf16x8*)&As[(mt * 16 + r16) * 32 + quad * 8];
            acc[mt] = __builtin_amdgcn_mfma_f32_16x16x32_bf16(af, bfr, acc[mt], 0, 0, 0);
        }
    }

    const int n = n0 + w * 16 + r16;
    if (n < 288) {
        const float bias = (n >= 32) ? g1b[n - 32] : 0.f;
        #pragma unroll
        for (int mt = 0; mt < 4; ++mt)
            #pragma unroll
            for (int i = 0; i < 4; ++i) {
                const int m = m0 + mt * 16 + quad * 4 + i;
                R[(size_t)m * RS + n] = acc[mt][i] + bias;
            }
    } else if (n < 800) {
        const int d = n - 288;
        const float bias = vb[d];
        #pragma unroll
        for (int mt = 0; mt < 4; ++mt) {
            ushort4 h4, l4;
            #pragma unroll
            for (int i = 0; i < 4; ++i) {
                float v = acc[mt][i] + bias;
                unsigned short hi = f2bf(v);
                ((unsigned short*)&h4)[i] = hi;
                ((unsigned short*)&l4)[i] = f2bf(v - bf2f(hi));
            }
            const size_t vo = (size_t)d * 2048 + m0 + mt * 16 + quad * 4;
            *(ushort4*)&Vthi[vo] = h4;
            *(ushort4*)&Vtlo[vo] = l4;
        }
    }
}

// ---------------- phasors, jk/jq, gate + compact jkT (verified R7) ----------------
__global__ __launch_bounds__(256) void k_phasor(
    const float* __restrict__ R,
    const float* __restrict__ g2w, const float* __restrict__ g2b,
    float* __restrict__ scal, float* __restrict__ jkT)
{
    const int row = blockIdx.x * 4 + (threadIdx.x >> 6);
    const int lane = threadIdx.x & 63;
    const int b = row >> 10, l = row & (L_ - 1);
    float* sc = scal + (size_t)row * 128;
    const float* r = R + (size_t)row * RS;

    float part = 0.f;
    #pragma unroll
    for (int j = 0; j < 4; ++j) {
        float v = r[32 + lane * 4 + j];
        float h = 0.5f * v * (1.0f + erff(v * 0.70710678f));
        part += h * g2w[lane * 4 + j];
    }
    #pragma unroll
    for (int off = 32; off > 0; off >>= 1) part += __shfl_down(part, off, 64);
    if (lane == 0) sc[112] = 1.0f / (1.0f + expf(-(part + g2b[0])));

    float pr = 1.f, pim = 0.f;
    if (lane < 32) {
        float a = tanhf(r[lane]) * PI_F;
        float sv, cv;
        sincosf(a, &sv, &cv);
        int t = lane & 15;
        if (lane < 16) { sc[t] = cv; sc[16 + t] = sv; }
        else           { sc[32 + t] = cv; sc[48 + t] = sv; }
        pr = cv; pim = sv;
    }
    #pragma unroll
    for (int m = 4; m <= 8; m <<= 1) {
        float orr = __shfl_xor(pr, m, 64);
        float oii = __shfl_xor(pim, m, 64);
        float nr = pr * orr - pim * oii;
        float ni = pr * oii + pim * orr;
        pr = nr; pim = ni;
    }
    if (lane < 4) {
        sc[64 + lane] = pr; sc[68 + lane] = pim;
        jkT[(size_t)(b * 8 + lane) * L_ + l]     = pr;
        jkT[(size_t)(b * 8 + 4 + lane) * L_ + l] = pim;
    } else if (lane >= 16 && lane < 20) {
        sc[72 + lane - 16] = pr; sc[76 + lane - 16] = pim;
    }
}

// ---------------- wide block scan: 16 channels (verified R8) ----------------
__global__ __launch_bounds__(256) void k_scan16(
    const float* __restrict__ jkT, float* __restrict__ kmT)
{
    const int bx = blockIdx.x;
    const int tid = threadIdx.x;
    const int lane = tid & 63, wv = tid >> 6;
    __shared__ float wtot[4];
    float4 v = ((const float4*)(jkT + (size_t)bx * L_))[tid];
    float s = v.x + v.y + v.z + v.w;
    float incl = s;
    #pragma unroll
    for (int off = 1; off < 64; off <<= 1) {
        float o = __shfl_up(incl, off, 64);
        if (lane >= off) incl += o;
    }
    if (lane == 63) wtot[wv] = incl;
    __syncthreads();
    float pre = incl - s;
    for (int w2 = 0; w2 < wv; ++w2) pre += wtot[w2];
    float4 out;
    out.x = pre;
    out.y = pre + v.x;
    out.z = out.y + v.y;
    out.w = out.z + v.z;
    ((float4*)(kmT + (size_t)bx * L_))[tid] = out;
}

// ---------------- build: wgv inline + Qf/Kf rows (verified R8) ----------------
__global__ __launch_bounds__(256) void k_build(
    const float* __restrict__ scal, const float* __restrict__ kmT,
    const float* __restrict__ res_scale, const float* __restrict__ res_thr,
    const float* __restrict__ sur_scale, const float* __restrict__ sur_bias,
    const float* __restrict__ setw,
    unsigned short* __restrict__ Qf, unsigned short* __restrict__ Kf)
{
    const int rowi = blockIdx.x * 8 + (threadIdx.x >> 5);
    const int sub = threadIdx.x & 31;
    const int b = rowi >> 10, l = rowi & (L_ - 1);
    const float* sc = scal + (size_t)rowi * 128;

    float mag = 0.f;
    #pragma unroll
    for (int pp = 0; pp < 4; ++pp) {
        float kmr = kmT[(size_t)(b * 8 + pp) * L_ + l];
        float kmi = kmT[(size_t)(b * 8 + 4 + pp) * L_ + l];
        float jqr = sc[72 + pp], jqi = sc[76 + pp];
        float re = kmr * jqr + kmi * jqi;
        float im = kmi * jqr - kmr * jqi;
        mag += sqrtf(re * re + im * im);
    }
    mag *= 0.25f;
    float posn = fmaxf((float)l, 1.0f);
    float nres = mag / sqrtf(posn);
    float scl = fminf(fmaxf(res_scale[0], 1.0f), 20.0f);
    float thr = fminf(fmaxf(res_thr[0], 0.1f), 0.9f);
    float sur = 0.5f * (1.0f - tanhf(scl * (nres - thr)));
    float wgv = 1.0f / (1.0f + expf(-(sur_scale[0] * (sur - 0.5f) + sur_bias[0])));

    const float gate = sc[112];
    float s0 = setw[0], s1 = setw[1], s2 = setw[2], s3 = setw[3];
    float mx = fmaxf(fmaxf(s0, s1), fmaxf(s2, s3));
    float e0 = expf(s0 - mx), e1 = expf(s1 - mx), e2 = expf(s2 - mx), e3 = expf(s3 - mx);
    float esum = e0 + e1 + e2 + e3;
    const float qs = 0.2f * gate;

    unsigned* qp = (unsigned*)(Qf + (size_t)rowi * 64);
    unsigned* kp = (unsigned*)(Kf + (size_t)rowi * 64);
    if (sub < 16) {
        float wgrp = ((sub >> 2) == 0 ? e0 : (sub >> 2) == 1 ? e1 : (sub >> 2) == 2 ? e2 : e3) / esum;
        qp[sub] = pack2(qs * wgrp * sc[32 + sub], qs * wgrp * sc[48 + sub]);
        kp[sub] = pack2(wgv * sc[sub], wgv * sc[16 + sub]);
    } else if (sub < 20) {
        int p = sub - 16;
        qp[16 + p] = pack2(qs * sc[72 + p], qs * sc[76 + p]);
        kp[16 + p] = pack2(wgv * sc[64 + p], wgv * sc[68 + p]);
    } else {
        qp[sub] = 0u; kp[sub] = 0u;
    }
}

// ---------------- build A (tril 64x64 tiles) (verified R3/R8) ----------------
__global__ __launch_bounds__(256) void k_buildA(
    const unsigned short* __restrict__ Qf, const unsigned short* __restrict__ Kf,
    const float* __restrict__ scal, const float* __restrict__ gtab,
    const float* __restrict__ posw,
    unsigned short* __restrict__ Ahi, unsigned short* __restrict__ Alo)
{
    const int bx = blockIdx.x;
    const int b = bx / 136;
    const int r = bx % 136;
    int ti = 0;
    while ((ti + 1) * (ti + 2) / 2 <= r) ++ti;
    const int tj = r - ti * (ti + 1) / 2;

    __shared__ unsigned short Qs[64 * 72];
    __shared__ unsigned short Ks[64 * 72];
    const int tid = threadIdx.x;
    const int srow = tid >> 2;
    const int sc16 = (tid & 3) * 16;
    {
        const unsigned short* qsrc = Qf + ((size_t)(b * L_ + ti * 64 + srow)) * 64 + sc16;
        const unsigned short* ksrc = Kf + ((size_t)(b * L_ + tj * 64 + srow)) * 64 + sc16;
        *(int4*)&Qs[srow * 72 + sc16]     = *(const int4*)(qsrc);
        *(int4*)&Qs[srow * 72 + sc16 + 8] = *(const int4*)(qsrc + 8);
        *(int4*)&Ks[srow * 72 + sc16]     = *(const int4*)(ksrc);
        *(int4*)&Ks[srow * 72 + sc16 + 8] = *(const int4*)(ksrc + 8);
    }
    __syncthreads();

    const int w = tid >> 6;
    const int lane = tid & 63;
    const int quad = lane >> 4, r16 = lane & 15;
    f32x4 acc[4];
    #pragma unroll
    for (int mt = 0; mt < 4; ++mt) acc[mt] = (f32x4){0.f, 0.f, 0.f, 0.f};
    #pragma unroll
    for (int kk = 0; kk < 2; ++kk) {
        bf16x8 bfr = *(const bf16x8*)&Ks[(w * 16 + r16) * 72 + kk * 32 + quad * 8];
        #pragma unroll
        for (int mt = 0; mt < 4; ++mt) {
            bf16x8 af = *(const bf16x8*)&Qs[(mt * 16 + r16) * 72 + kk * 32 + quad * 8];
            acc[mt] = __builtin_amdgcn_mfma_f32_16x16x32_bf16(af, bfr, acc[mt], 0, 0, 0);
        }
    }
    const float sw = 1.0f / (1.0f + expf(-posw[0]));
    const int lp = tj * 64 + w * 16 + r16;
    #pragma unroll
    for (int mt = 0; mt < 4; ++mt) {
        #pragma unroll
        for (int i = 0; i < 4; ++i) {
            const int l = ti * 64 + mt * 16 + quad * 4 + i;
            const int dl = l - lp;
            float v = 0.f;
            if (dl >= 0) {
                float gate = scal[((size_t)(b * L_ + l)) * 128 + 112];
                v = acc[mt][i] + (1.0f - gate) * sw * gtab[dl];
            }
            unsigned short hi = f2bf(v);
            unsigned short lo = f2bf(v - bf2f(hi));
            const size_t off = ((size_t)(b * L_ + l)) * 1024 + lp;
            Ahi[off] = hi;
            Alo[off] = lo;
        }
    }
}

// ---------------- AV GEMM, h-split + b-flip balance (verified R8) ----------------
__global__ __launch_bounds__(256) void k_avH(
    const unsigned short* __restrict__ Ahi, const unsigned short* __restrict__ Alo,
    const unsigned short* __restrict__ Vthi, const unsigned short* __restrict__ Vtlo,
    float* __restrict__ parts)
{
    const int bx = blockIdx.x;          // b(1)|ti0(4)|nj(3)|h(1) = 512
    const int h  = bx & 1;
    const int nj = (bx >> 1) & 7;
    const int ti0 = (bx >> 4) & 15;
    const int b  = bx >> 8;
    const int ti = b ? (15 - ti0) : ti0;
    const int m0 = ti * 64, n0 = nj * 64;
    const int nh = (ti + 2) >> 1;
    const int kbeg = (h ? nh : 0) * 64;
    const int kend = (h ? (ti + 1) : nh) * 64;
    float* prt = parts + (size_t)h * NROW * 512;

    __shared__ unsigned short Ash[64 * 32];
    __shared__ unsigned short Asl[64 * 32];
    __shared__ unsigned short Bsh[64 * 32];
    __shared__ unsigned short Bsl[64 * 32];
    const int tid = threadIdx.x;
    const int w = tid >> 6;
    const int lane = tid & 63;
    const int srow = tid >> 2;
    const int scol = (tid & 3) * 8;
    const int quad = lane >> 4, r16 = lane & 15;

    f32x4 acc[4];
    #pragma unroll
    for (int mt = 0; mt < 4; ++mt) acc[mt] = (f32x4){0.f, 0.f, 0.f, 0.f};

    const unsigned short* aph = Ahi + ((size_t)(b * L_ + m0 + srow)) * 1024 + scol;
    const unsigned short* apl = Alo + ((size_t)(b * L_ + m0 + srow)) * 1024 + scol;
    const unsigned short* bph = Vthi + (size_t)(n0 + srow) * 2048 + b * L_ + scol;
    const unsigned short* bpl = Vtlo + (size_t)(n0 + srow) * 2048 + b * L_ + scol;

    for (int k0 = kbeg; k0 < kend; k0 += 32) {
        int4 ah = *(const int4*)(aph + k0);
        int4 al = *(const int4*)(apl + k0);
        int4 bh = *(const int4*)(bph + k0);
        int4 bl = *(const int4*)(bpl + k0);
        __syncthreads();
        *(int4*)&Ash[srow * 32 + scol] = ah;
        *(int4*)&Asl[srow * 32 + scol] = al;
        *(int4*)&Bsh[srow * 32 + scol] = bh;
        *(int4*)&Bsl[srow * 32 + scol] = bl;
        __syncthreads();
        bf16x8 bh8 = *(const bf16x8*)&Bsh[(w * 16 + r16) * 32 + quad * 8];
        bf16x8 bl8 = *(const bf16x8*)&Bsl[(w * 16 + r16) * 32 + quad * 8];
        #pragma unroll
        for (int mt = 0; mt < 4; ++mt) {
            bf16x8 ah8 = *(const bf16x8*)&Ash[(mt * 16 + r16) * 32 + quad * 8];
            bf16x8 al8 = *(const bf16x8*)&Asl[(mt * 16 + r16) * 32 + quad * 8];
            acc[mt] = __builtin_amdgcn_mfma_f32_16x16x32_bf16(ah8, bh8, acc[mt], 0, 0, 0);
            acc[mt] = __builtin_amdgcn_mfma_f32_16x16x32_bf16(ah8, bl8, acc[mt], 0, 0, 0);
            acc[mt] = __builtin_amdgcn_mfma_f32_16x16x32_bf16(al8, bh8, acc[mt], 0, 0, 0);
        }
    }
    const int n = n0 + w * 16 + r16;
    #pragma unroll
    for (int mt = 0; mt < 4; ++mt)
        #pragma unroll
        for (int i = 0; i < 4; ++i)
            prt[((size_t)(b * L_ + m0 + mt * 16 + quad * 4 + i)) * 512 + n] = acc[mt][i];
}

// ---------------- LN: y = (p0+p1)/nf, LayerNorm, bf16 out (R3 k_ln + parts add) ----------------
__global__ __launch_bounds__(512) void k_ln2(
    const float* __restrict__ parts,
    const float* __restrict__ lng, const float* __restrict__ lnb,
    unsigned short* __restrict__ locb)
{
    const int row = blockIdx.x;
    const int l = row & (L_ - 1);
    const int d = threadIdx.x;
    __shared__ float red[16];
    float y = (parts[(size_t)row * 512 + d]
             + parts[(size_t)NROW * 512 + (size_t)row * 512 + d])
            / sqrtf(4.0f * (float)(l + 1));
    float s = y, s2v = y * y;
    #pragma unroll
    for (int off = 32; off > 0; off >>= 1) {
        s   += __shfl_down(s, off, 64);
        s2v += __shfl_down(s2v, off, 64);
    }
    const int lane = d & 63, wv = d >> 6;
    if (lane == 0) { red[wv] = s; red[8 + wv] = s2v; }
    __syncthreads();
    float su = 0.f, sq = 0.f;
    #pragma unroll
    for (int w2 = 0; w2 < 8; ++w2) { su += red[w2]; sq += red[8 + w2]; }
    float mu = su * (1.0f / 512.0f);
    float var = sq * (1.0f / 512.0f) - mu * mu;
    float rstd = rsqrtf(var + 1e-5f);
    float yn = (y - mu) * rstd * lng[d] + lnb[d];
    locb[(size_t)row * 512 + d] = f2bf(yn);
}

// ---------------- out GEMM (verified R1/R3): out = x + locb @ OWt^T + out_b ----------------
__global__ __launch_bounds__(256) void k_gemm_out(
    const unsigned short* __restrict__ A,    // locb [2048][512] bf16
    const unsigned short* __restrict__ Bt,   // OWt [512][512] bf16 n-major
    const float* __restrict__ bias, const float* __restrict__ resid,
    float* __restrict__ out)
{
    __shared__ unsigned short As[64 * 32];
    __shared__ unsigned short Bs[64 * 32];
    const int tid = threadIdx.x;
    const int w = tid >> 6;
    const int lane = tid & 63;
    const int m0 = blockIdx.y * 64;
    const int n0 = blockIdx.x * 64;
    const int srow = tid >> 2;
    const int scol = (tid & 3) * 8;
    const int quad = lane >> 4, r16 = lane & 15;

    f32x4 acc[4];
    #pragma unroll
    for (int mt = 0; mt < 4; ++mt) acc[mt] = (f32x4){0.f, 0.f, 0.f, 0.f};

    const unsigned short* ap = A  + (size_t)(m0 + srow) * 512 + scol;
    const unsigned short* bp = Bt + (size_t)(n0 + srow) * 512 + scol;

    for (int k0 = 0; k0 < 512; k0 += 32) {
        int4 av = *(const int4*)(ap + k0);
        int4 bv = *(const int4*)(bp + k0);
        __syncthreads();
        *(int4*)&As[srow * 32 + scol] = av;
        *(int4*)&Bs[srow * 32 + scol] = bv;
        __syncthreads();
        bf16x8 bfr = *(const bf16x8*)&Bs[(w * 16 + r16) * 32 + quad * 8];
        #pragma unroll
        for (int mt = 0; mt < 4; ++mt) {
            bf16x8 af = *(const bf16x8*)&As[(mt * 16 + r16) * 32 + quad * 8];
            acc[mt] = __builtin_amdgcn_mfma_f32_16x16x32_bf16(af, bfr, acc[mt], 0, 0, 0);
        }
    }
    const int n = n0 + w * 16 + r16;
    const float bn = bias[n];
    #pragma unroll
    for (int mt = 0; mt < 4; ++mt) {
        #pragma unroll
        for (int i = 0; i < 4; ++i) {
            const int m = m0 + mt * 16 + quad * 4 + i;
            out[(size_t)m * 512 + n] = acc[mt][i] + bn + resid[(size_t)m * 512 + n];
        }
    }
}

extern "C" void kernel_launch(void* const* d_in, const int* in_sizes, int n_in,
                              void* d_out, int out_size, void* d_ws, size_t ws_size,
                              hipStream_t stream)
{
    const float* x      = (const float*)d_in[0];
    const float* keyw   = (const float*)d_in[1];
    const float* qryw   = (const float*)d_in[2];
    const float* vw     = (const float*)d_in[4];
    const float* vb     = (const float*)d_in[5];
    const float* lng    = (const float*)d_in[6];
    const float* lnb    = (const float*)d_in[7];
    const float* outw   = (const float*)d_in[8];
    const float* outb   = (const float*)d_in[9];
    const float* setw   = (const float*)d_in[10];
    const float* pf     = (const float*)d_in[11];
    const float* posw   = (const float*)d_in[12];
    const float* g1w    = (const float*)d_in[13];
    const float* g1b    = (const float*)d_in[14];
    const float* g2w    = (const float*)d_in[15];
    const float* g2b    = (const float*)d_in[16];
    const float* sscale = (const float*)d_in[19];
    const float* sbias  = (const float*)d_in[20];
    const float* rscale = (const float*)d_in[21];
    const float* rthr   = (const float*)d_in[22];

    char* wsb = (char*)d_ws;
    float*          R      = (float*)(wsb + 0);                  // 2.25 MiB
    float*          scal   = (float*)(wsb + 2359296);            // 1 MiB
    float*          parts  = (float*)(wsb + 3407872);            // 8 MiB (2 slots)
    unsigned short* W      = (unsigned short*)(wsb + 11796480);  // 1.375 MiB
    unsigned short* Vthi   = (unsigned short*)(wsb + 13238272);  // 2 MiB
    unsigned short* Vtlo   = (unsigned short*)(wsb + 15335424);  // 2 MiB
    unsigned short* Qf     = (unsigned short*)(wsb + 17432576);  // 256 KiB
    unsigned short* Kf     = (unsigned short*)(wsb + 17694720);  // 256 KiB
    float*          gtab   = (float*)(wsb + 17956864);           // 4 KiB
    float*          jkT    = (float*)(wsb + 17977344);           // 64 KiB
    float*          kmT    = (float*)(wsb + 18042880);           // 64 KiB
    unsigned short* Ahi    = (unsigned short*)(wsb + 18108416);  // 4 MiB
    unsigned short* Alo    = (unsigned short*)(wsb + 22302720);  // 4 MiB
    unsigned short* xb     = (unsigned short*)(wsb + 26497024);  // 2 MiB
    unsigned short* locb   = (unsigned short*)(wsb + 28594176);  // 2 MiB

    float* out = (float*)d_out;

    k_prep_w<<<305, 256, 0, stream>>>(keyw, qryw, g1w, vw, outw, x, pf, W, xb, gtab);
    k_gemm1v<<<dim3(14, 32), 256, 0, stream>>>(xb, W, g1b, vb, R, Vthi, Vtlo);
    k_phasor<<<NROW / 4, 256, 0, stream>>>(R, g2w, g2b, scal, jkT);
    k_scan16<<<16, 256, 0, stream>>>(jkT, kmT);
    k_build<<<256, 256, 0, stream>>>(scal, kmT, rscale, rthr, sscale, sbias, setw, Qf, Kf);
    k_buildA<<<2 * 136, 256, 0, stream>>>(Qf, Kf, scal, gtab, posw, Ahi, Alo);
    k_avH<<<512, 256, 0, stream>>>(Ahi, Alo, Vthi, Vtlo, parts);
    k_ln2<<<NROW, 512, 0, stream>>>(parts, lng, lnb, locb);
    k_gemm_out<<<dim3(8, 32), 256, 0, stream>>>(locb, W + (size_t)896 * 512, outb, x, out);
}